// Round 8
// baseline (494.205 us; speedup 1.0000x reference)
//
#include <hip/hip_runtime.h>

#define N_NODES 20000
#define N_EDGES 320000
#define N_REL   100
#define FDIM    256
#define NHEAD   8
#define HDIM    32
#define SCAN_BLOCKS ((N_NODES + 255) / 256)   // 79

using short8 = __attribute__((ext_vector_type(8))) short;   // 8 bf16 in 4 VGPRs
using f32x4  = __attribute__((ext_vector_type(4))) float;

__device__ inline unsigned short f2bf(float f) {
    union { float f; unsigned int u; } v; v.f = f;
    unsigned int r = v.u + 0x7fff + ((v.u >> 16) & 1);   // RNE
    return (unsigned short)(r >> 16);
}
__device__ inline float bf2f(unsigned short u) {
    union { unsigned int i; float f; } v; v.i = ((unsigned int)u) << 16; return v.f;
}
__device__ inline float4 bf4(ushort4 u) {
    return make_float4(bf2f(u.x), bf2f(u.y), bf2f(u.z), bf2f(u.w));
}
// unpack 8 bf16 (uint4) -> 8 fp32
__device__ inline void unpack8(float* d, uint4 u) {
    union { unsigned int u; float f; } t;
    t.u = u.x << 16;         d[0] = t.f;
    t.u = u.x & 0xffff0000u; d[1] = t.f;
    t.u = u.y << 16;         d[2] = t.f;
    t.u = u.y & 0xffff0000u; d[3] = t.f;
    t.u = u.z << 16;         d[4] = t.f;
    t.u = u.z & 0xffff0000u; d[5] = t.f;
    t.u = u.w << 16;         d[6] = t.f;
    t.u = u.w & 0xffff0000u; d[7] = t.f;
}
// acc[k] += w * bf16(u)[k], 8 elements
__device__ inline void fma8(float* acc, uint4 u, float w) {
    union { unsigned int u; float f; } t;
    t.u = u.x << 16;         acc[0] += w * t.f;
    t.u = u.x & 0xffff0000u; acc[1] += w * t.f;
    t.u = u.y << 16;         acc[2] += w * t.f;
    t.u = u.y & 0xffff0000u; acc[3] += w * t.f;
    t.u = u.z << 16;         acc[4] += w * t.f;
    t.u = u.z & 0xffff0000u; acc[5] += w * t.f;
    t.u = u.w << 16;         acc[6] += w * t.f;
    t.u = u.w & 0xffff0000u; acc[7] += w * t.f;
}
// direct global -> LDS DMA, 16 bytes per lane (gfx950 global_load_lds_dwordx4)
__device__ __forceinline__ void g2lds16(const unsigned short* g, unsigned short* l) {
    __builtin_amdgcn_global_load_lds(
        (const __attribute__((address_space(1))) unsigned int*)g,
        (__attribute__((address_space(3))) unsigned int*)l,
        16, 0, 0);
}

// bijective XCD swizzle (m204)
__device__ inline void xcd_tile(int* m0, int* n0, int tm, int tn) {
    int nwg  = gridDim.x * gridDim.y;
    int wgid = blockIdx.x + blockIdx.y * gridDim.x;
    int q = nwg >> 3, r = nwg & 7;
    int xcd = wgid & 7, pos = wgid >> 3;
    int nid = (xcd < r ? xcd * (q + 1) : r * (q + 1) + (xcd - r) * q) + pos;
    int gy = gridDim.y;
    int bx = nid / gy;
    int by = nid - bx * gy;
    *m0 = bx * tm;
    *n0 = by * tn;
}

// ---------------------------------------------------------------------------
// Fused LayerNorm (node rows + rel rows in one grid) -> bf16. One wave/row.
// ---------------------------------------------------------------------------
__global__ __launch_bounds__(64) void ln_fused_kernel(
    const float* __restrict__ ent, const float* __restrict__ rel,
    const float* __restrict__ ge, const float* __restrict__ be,
    const float* __restrict__ gr, const float* __restrict__ br,
    unsigned short* __restrict__ xb, unsigned short* __restrict__ rlnb)
{
    int row = blockIdx.x;
    const float *in, *g, *b; unsigned short* out; int r;
    if (row < N_NODES) { in = ent; g = ge; b = be; out = xb;   r = row; }
    else               { in = rel; g = gr; b = br; out = rlnb; r = row - N_NODES; }
    int tid = threadIdx.x;
    const float4 v = *(const float4*)(in + (size_t)r * FDIM + tid * 4);
    float s = v.x + v.y + v.z + v.w;
    float q = v.x * v.x + v.y * v.y + v.z * v.z + v.w * v.w;
    #pragma unroll
    for (int d = 1; d < 64; d <<= 1) { s += __shfl_xor(s, d); q += __shfl_xor(q, d); }
    float mean = s * (1.0f / FDIM);
    float var  = q * (1.0f / FDIM) - mean * mean;
    float inv  = rsqrtf(var + 1e-5f);
    float4 gg = *(const float4*)(g + tid * 4);
    float4 bb = *(const float4*)(b + tid * 4);
    ushort4 o;
    o.x = f2bf((v.x - mean) * inv * gg.x + bb.x);
    o.y = f2bf((v.y - mean) * inv * gg.y + bb.y);
    o.z = f2bf((v.z - mean) * inv * gg.z + bb.z);
    o.w = f2bf((v.w - mean) * inv * gg.w + bb.w);
    *(ushort4*)(out + (size_t)r * FDIM + tid * 4) = o;
}

// rst = bf2f(feat) + ent (fp32) ; y = LN(rst) (bf16)
__global__ __launch_bounds__(64) void rst_ln_kernel(
    const unsigned short* __restrict__ feat, const float* __restrict__ ent,
    const float* __restrict__ g, const float* __restrict__ b,
    float* __restrict__ rst, unsigned short* __restrict__ y)
{
    int row = blockIdx.x;
    int tid = threadIdx.x;
    const float4 f = bf4(*(const ushort4*)(feat + (size_t)row * FDIM + tid * 4));
    const float4 e = *(const float4*)(ent + (size_t)row * FDIM + tid * 4);
    float4 r;
    r.x = f.x + e.x; r.y = f.y + e.y; r.z = f.z + e.z; r.w = f.w + e.w;
    *(float4*)(rst + (size_t)row * FDIM + tid * 4) = r;
    float s = r.x + r.y + r.z + r.w;
    float q = r.x * r.x + r.y * r.y + r.z * r.z + r.w * r.w;
    #pragma unroll
    for (int d = 1; d < 64; d <<= 1) { s += __shfl_xor(s, d); q += __shfl_xor(q, d); }
    float mean = s * (1.0f / FDIM);
    float var  = q * (1.0f / FDIM) - mean * mean;
    float inv  = rsqrtf(var + 1e-5f);
    float4 gg = *(const float4*)(g + tid * 4);
    float4 bb = *(const float4*)(b + tid * 4);
    ushort4 o;
    o.x = f2bf((r.x - mean) * inv * gg.x + bb.x);
    o.y = f2bf((r.y - mean) * inv * gg.y + bb.y);
    o.z = f2bf((r.z - mean) * inv * gg.z + bb.z);
    o.w = f2bf((r.w - mean) * inv * gg.w + bb.w);
    *(ushort4*)(y + (size_t)row * FDIM + tid * 4) = o;
}

// ---------------------------------------------------------------------------
// Fused weight transposes: all 6 fp32[K,N] -> bf16[N,K] in one dispatch.
// ---------------------------------------------------------------------------
__global__ void transpose_all_kernel(
    const float* __restrict__ Wh, const float* __restrict__ Wt_,
    const float* __restrict__ We, const float* __restrict__ Wr,
    const float* __restrict__ W1, const float* __restrict__ W2,
    unsigned short* __restrict__ WtP, unsigned short* __restrict__ WtR,
    unsigned short* __restrict__ W1t, unsigned short* __restrict__ W2t)
{
    int idx = blockIdx.x * 256 + threadIdx.x;
    if (idx < 196608) {
        int seg = idx >> 16, r = idx & 65535;
        const float* W = (seg == 0) ? Wh : (seg == 1) ? Wt_ : We;
        int n = r >> 8, k = r & 255;
        WtP[idx] = f2bf(W[k * 256 + n]);
    } else if (idx < 262144) {
        int r = idx - 196608;
        int n = r >> 8, k = r & 255;
        WtR[r] = f2bf(Wr[k * 256 + n]);
    } else if (idx < 524288) {
        int r = idx - 262144;                 // K=256, N=1024
        int n = r >> 8, k = r & 255;
        W1t[r] = f2bf(W1[k * 1024 + n]);
    } else if (idx < 786432) {
        int r = idx - 524288;                 // K=1024, N=256
        int n = r >> 10, k = r & 1023;
        W2t[r] = f2bf(W2[k * 256 + n]);
    }
}

// ---------------------------------------------------------------------------
// K=256 single-stage MFMA GEMM: C[M,N] = A[M,256] @ Bt[N,256]^T (+bias)(relu)
// -> bf16 out. 128x128 tile; ENTIRE K staged once into 128 KiB LDS
// (A 64 KiB + B 64 KiB) -> exactly ONE barrier/latency-exposure per block
// (vs 8 with the BK=32 dbuf loop: MfmaUtil was 4.6%, 60 us for proj).
// Rows are 512 B -> naive reads would be 16-way bank-conflicted; fixed via
// rule-#21: linear global_load_lds dest + inverse-XOR-swizzled global SOURCE
// (koff = tcol ^ ((row&7)<<4)) + the same XOR on the ds_read address (2-way,
// free per m136). No inner barriers: 8 unrolled ds_read+MFMA steps.
// ---------------------------------------------------------------------------
__global__ __launch_bounds__(256) void mfma_gemm_k256(
    const unsigned short* __restrict__ A, const unsigned short* __restrict__ Bt,
    const float* __restrict__ bias, unsigned short* __restrict__ Cb,
    int M, int N, int relu)
{
    __shared__ unsigned short As[128 * 256];   // 64 KiB
    __shared__ unsigned short Bs[128 * 256];   // 64 KiB
    int tid  = threadIdx.x;
    int wave = tid >> 6, lane = tid & 63;
    int quad = lane >> 4, l16 = lane & 15;
    int m0, n0;
    xcd_tile(&m0, &n0, 128, 128);
    int wr = (wave >> 1) * 64, wc = (wave & 1) * 64;

    // stage: 16 issues/thread/matrix; per-wave LDS dest = wavebase + lane*16
    int trow = tid >> 5;                 // 0..7 (row within 8-row group)
    int tcol = (tid & 31) * 16;          // byte offset within 512B row
    #pragma unroll
    for (int j = 0; j < 16; ++j) {
        int row  = j * 8 + trow;         // 0..127
        int koff = tcol ^ ((row & 7) << 4);   // inverse-swizzled source bytes
        int gra  = m0 + row; if (gra >= M) gra = M - 1;
        g2lds16(A  + (size_t)gra * 256        + (koff >> 1),
                As + row * 256 + (tcol >> 1));
        g2lds16(Bt + (size_t)(n0 + row) * 256 + (koff >> 1),
                Bs + row * 256 + (tcol >> 1));
    }
    __syncthreads();                     // the ONE latency exposure

    f32x4 acc[4][4] = {};
    #pragma unroll
    for (int kk = 0; kk < 8; ++kk) {
        short8 af[4], bfr[4];
        int kb = kk * 64 + quad * 16;    // byte offset of this K-fragment
        #pragma unroll
        for (int i = 0; i < 4; ++i) {
            int row = wr + i * 16 + l16;
            int off = row * 512 + (kb ^ ((row & 7) << 4));
            af[i] = *(const short8*)((const char*)As + off);
        }
        #pragma unroll
        for (int j = 0; j < 4; ++j) {
            int row = wc + j * 16 + l16;
            int off = row * 512 + (kb ^ ((row & 7) << 4));
            bfr[j] = *(const short8*)((const char*)Bs + off);
        }
        #pragma unroll
        for (int i = 0; i < 4; ++i)
            #pragma unroll
            for (int j = 0; j < 4; ++j)
                acc[i][j] = __builtin_amdgcn_mfma_f32_16x16x32_bf16(
                    af[i], bfr[j], acc[i][j], 0, 0, 0);
    }

    #pragma unroll
    for (int i = 0; i < 4; ++i) {
        #pragma unroll
        for (int j = 0; j < 4; ++j) {
            int col = n0 + wc + j * 16 + l16;
            float bsv = bias ? bias[col] : 0.0f;
            #pragma unroll
            for (int r = 0; r < 4; ++r) {
                int row = m0 + wr + i * 16 + quad * 4 + r;
                if (row < M) {
                    float v = acc[i][j][r] + bsv;
                    if (relu) v = fmaxf(v, 0.0f);
                    Cb[(size_t)row * N + col] = f2bf(v);
                }
            }
        }
    }
}

// ---------------------------------------------------------------------------
// 64x128-tile dbuf variant for FFN2 (K=1024): 4 waves, 4x2 frags.
// r8 tweak: ds_reads issued BEFORE the prefetch g2lds (avoids any
// conservative vmcnt wait blocking the LDS reads).
// ---------------------------------------------------------------------------
__global__ __launch_bounds__(256) void mfma_gemm64_bt(
    const unsigned short* __restrict__ A, const unsigned short* __restrict__ Bt,
    const float* __restrict__ bias, const float* __restrict__ add,
    float* __restrict__ Cf, int M, int K, int N)
{
    __shared__ unsigned short As[2][64 * 32];
    __shared__ unsigned short Bs[2][128 * 32];
    int tid  = threadIdx.x;
    int wave = tid >> 6, lane = tid & 63;
    int quad = lane >> 4, l16 = lane & 15;
    int m0, n0;
    xcd_tile(&m0, &n0, 64, 128);
    int wc = wave * 32;

    f32x4 acc[4][2] = {};

    int rA0 = tid >> 2, kA0 = (tid & 3) * 8;
    int cB0 = tid, cB1 = tid + 256;
    int rB0 = cB0 >> 2, kB0 = (cB0 & 3) * 8;
    int rB1 = cB1 >> 2, kB1 = (cB1 & 3) * 8;
    int rA = m0 + rA0; if (rA >= M) rA = M - 1;
    const unsigned short* gA  = A + (size_t)rA * K + kA0;
    const unsigned short* gB0 = Bt + (size_t)(n0 + rB0) * K + kB0;
    const unsigned short* gB1 = Bt + (size_t)(n0 + rB1) * K + kB1;

    g2lds16(gA,  As[0] + tid * 8);
    g2lds16(gB0, Bs[0] + cB0 * 8);
    g2lds16(gB1, Bs[0] + cB1 * 8);
    __syncthreads();

    int cur = 0;
    for (int k0 = 0; k0 < K; k0 += 32) {
        short8 af[4], bfr[2];
        #pragma unroll
        for (int i = 0; i < 4; ++i)
            af[i] = *(const short8*)(As[cur] + (i * 16 + l16) * 32 + quad * 8);
        #pragma unroll
        for (int j = 0; j < 2; ++j)
            bfr[j] = *(const short8*)(Bs[cur] + (wc + j * 16 + l16) * 32 + quad * 8);
        int k1 = k0 + 32;
        if (k1 < K) {
            int nb = cur ^ 1;
            g2lds16(gA + k1,  As[nb] + tid * 8);
            g2lds16(gB0 + k1, Bs[nb] + cB0 * 8);
            g2lds16(gB1 + k1, Bs[nb] + cB1 * 8);
        }
        #pragma unroll
        for (int i = 0; i < 4; ++i)
            #pragma unroll
            for (int j = 0; j < 2; ++j)
                acc[i][j] = __builtin_amdgcn_mfma_f32_16x16x32_bf16(
                    af[i], bfr[j], acc[i][j], 0, 0, 0);
        __syncthreads();
        cur ^= 1;
    }

    #pragma unroll
    for (int i = 0; i < 4; ++i) {
        #pragma unroll
        for (int j = 0; j < 2; ++j) {
            int col = n0 + wc + j * 16 + l16;
            float bsv = bias ? bias[col] : 0.0f;
            #pragma unroll
            for (int r = 0; r < 4; ++r) {
                int row = m0 + i * 16 + quad * 4 + r;
                if (row < M) {
                    float v = acc[i][j][r] + bsv;
                    if (add) v += add[(size_t)row * N + col];
                    Cf[(size_t)row * N + col] = v;
                }
            }
        }
    }
}

// ---------------------------------------------------------------------------
// Graph plumbing: degree count -> 3-phase parallel scan -> scatter
// ---------------------------------------------------------------------------
__global__ void count_kernel(const int* __restrict__ dst, int* __restrict__ deg, int E)
{
    int i = blockIdx.x * blockDim.x + threadIdx.x;
    if (i < E) atomicAdd(&deg[dst[i]], 1);
}

__global__ __launch_bounds__(256) void scan1_kernel(
    const int* __restrict__ deg, int* __restrict__ offsets, int* __restrict__ bsum, int n)
{
    __shared__ int tmp[256];
    int tid = threadIdx.x;
    int i = blockIdx.x * 256 + tid;
    int v = (i < n) ? deg[i] : 0;
    tmp[tid] = v;
    __syncthreads();
    for (int d = 1; d < 256; d <<= 1) {
        int u = (tid >= d) ? tmp[tid - d] : 0;
        __syncthreads();
        tmp[tid] += u;
        __syncthreads();
    }
    if (i < n) offsets[i] = tmp[tid] - v;
    if (tid == 255) bsum[blockIdx.x] = tmp[255];
}

__global__ __launch_bounds__(128) void scan2_kernel(int* __restrict__ bsum, int nb)
{
    __shared__ int tmp[128];
    int tid = threadIdx.x;
    int v = (tid < nb) ? bsum[tid] : 0;
    tmp[tid] = v;
    __syncthreads();
    for (int d = 1; d < 128; d <<= 1) {
        int u = (tid >= d) ? tmp[tid - d] : 0;
        __syncthreads();
        tmp[tid] += u;
        __syncthreads();
    }
    if (tid < nb) bsum[tid] = tmp[tid] - v;
}

__global__ __launch_bounds__(256) void scan3_kernel(
    const int* __restrict__ deg, int* __restrict__ offsets,
    const int* __restrict__ bsum, int* __restrict__ cursor,
    float* __restrict__ logdeg, int n, int E)
{
    int i = blockIdx.x * 256 + threadIdx.x;
    if (i < n) {
        int o = offsets[i] + bsum[blockIdx.x];
        offsets[i] = o;
        cursor[i]  = o;
        logdeg[i]  = logf((float)deg[i]);
    }
    if (i == 0) offsets[n] = E;
}

__global__ void scatter_kernel(const int* __restrict__ dst, const int* __restrict__ src,
                               const int* __restrict__ rid, int* __restrict__ cursor,
                               int* __restrict__ csr_src, int* __restrict__ csr_rid, int E)
{
    int i = blockIdx.x * blockDim.x + threadIdx.x;
    if (i < E) {
        int p = atomicAdd(&cursor[dst[i]], 1);
        csr_src[p] = src[i];
        csr_rid[p] = rid[i];
    }
}

// ---------------------------------------------------------------------------
// CSR edge attention (r1-proven structure). One wave per dst node (4/block),
// 16 lanes per edge, 8 edges per wave in flight. Stores unnormalized exp;
// writes 1/denom per (node,head) for diffuse.
// ---------------------------------------------------------------------------
__global__ __launch_bounds__(256) void edge_score_csr_kernel(
    const unsigned short* __restrict__ proj,   // [N,768]: fh | ftl | fen
    const unsigned short* __restrict__ frel,   // [R,256] bf16
    const float* __restrict__ attn,
    const int* __restrict__ csr_src, const int* __restrict__ csr_rid,
    const int* __restrict__ offsets, const float* __restrict__ logdeg,
    float* __restrict__ csr_a, float* __restrict__ invd, int n)
{
    int node = blockIdx.x * 4 + (threadIdx.x >> 6);
    if (node >= n) return;
    int tid = threadIdx.x & 63;
    int g = tid >> 4, li = tid & 15;
    int start = offsets[node], end = offsets[node + 1];
    float scale = logdeg[node] * (1.0f / 32.0f);

    float tv[16], at[16];
    {
        const unsigned short* tp = proj + (size_t)node * 768 + 256 + li * 16;
        uint4 a0 = *(const uint4*)tp, a1 = *(const uint4*)(tp + 8);
        unpack8(tv, a0); unpack8(tv + 8, a1);
        const float4* ap = (const float4*)(attn + li * 16);
        float4 f;
        f = ap[0]; at[0] = f.x; at[1] = f.y; at[2]  = f.z; at[3]  = f.w;
        f = ap[1]; at[4] = f.x; at[5] = f.y; at[6]  = f.z; at[7]  = f.w;
        f = ap[2]; at[8] = f.x; at[9] = f.y; at[10] = f.z; at[11] = f.w;
        f = ap[3]; at[12] = f.x; at[13] = f.y; at[14] = f.z; at[15] = f.w;
    }

    float denom = 0.f;
    for (int p = start; p < end; p += 8) {
        int  pe[2]; bool va[2]; uint4 h0[2], h1[2], r0[2], r1[2];
        #pragma unroll
        for (int t = 0; t < 2; ++t) {
            pe[t] = p + t * 4 + g;
            va[t] = pe[t] < end;
            int q = va[t] ? pe[t] : end - 1;
            int s = csr_src[q], r = csr_rid[q];
            const unsigned short* hp = proj + (size_t)s * 768 + li * 16;
            const unsigned short* rp = frel + (size_t)r * FDIM + li * 16;
            h0[t] = *(const uint4*)hp; h1[t] = *(const uint4*)(hp + 8);
            r0[t] = *(const uint4*)rp; r1[t] = *(const uint4*)(rp + 8);
        }
        #pragma unroll
        for (int t = 0; t < 2; ++t) {
            float hv[16], rv[16];
            unpack8(hv, h0[t]); unpack8(hv + 8, h1[t]);
            unpack8(rv, r0[t]); unpack8(rv + 8, r1[t]);
            float sum = 0.f;
            #pragma unroll
            for (int k = 0; k < 16; ++k) {
                float m = hv[k] * tv[k] * rv[k];
                m = (m > 0.f) ? m : 0.2f * m;
                sum += m * at[k];
            }
            sum += __shfl_xor(sum, 1);
            float ex = __expf(sum * scale);
            if (va[t] && ((li & 1) == 0)) {
                csr_a[(size_t)pe[t] * NHEAD + (li >> 1)] = ex;
                denom += ex;
            }
        }
    }
    denom += __shfl_xor(denom, 16);
    denom += __shfl_xor(denom, 32);
    if (g == 0 && (li & 1) == 0)
        invd[node * NHEAD + (li >> 1)] = 1.0f / denom;
}

// ---------------------------------------------------------------------------
// One PPR hop (bf16) — r1-proven structure. One wave per dst node (4/block);
// 16 lanes per edge, 16 edges in flight; cross-group reduce once/node.
// ---------------------------------------------------------------------------
__global__ __launch_bounds__(256) void diffuse_kernel(
    const unsigned short* __restrict__ fin, int fin_stride,
    const unsigned short* __restrict__ feat0,   // stride 768 (fen in proj)
    const float* __restrict__ a, const float* __restrict__ invd,
    const int* __restrict__ csr_src,
    const int* __restrict__ offsets, unsigned short* __restrict__ fout, int n)
{
    int node = blockIdx.x * 4 + (threadIdx.x >> 6);
    if (node >= n) return;
    int tid = threadIdx.x & 63;
    int g = tid >> 4, li = tid & 15;
    int hh = li >> 1;
    int start = offsets[node], end = offsets[node + 1];
    float wnorm = invd[node * NHEAD + hh];
    float acc[16] = {};

    for (int p = start; p < end; p += 16) {
        uint4 u0[4], u1[4]; float w[4];
        #pragma unroll
        for (int t = 0; t < 4; ++t) {
            int pe = p + t * 4 + g;
            int q = (pe < end) ? pe : end - 1;
            int s = csr_src[q];
            w[t] = (pe < end) ? a[(size_t)q * NHEAD + hh] : 0.0f;
            const unsigned short* rp = fin + (size_t)s * fin_stride + li * 16;
            u0[t] = *(const uint4*)(rp);
            u1[t] = *(const uint4*)(rp + 8);
        }
        #pragma unroll
        for (int t = 0; t < 4; ++t) {
            fma8(acc + 0, u0[t], w[t]);
            fma8(acc + 8, u1[t], w[t]);
        }
    }
    #pragma unroll
    for (int k = 0; k < 16; ++k) {
        acc[k] += __shfl_xor(acc[k], 16);
        acc[k] += __shfl_xor(acc[k], 32);
    }
    if (g == 0) {
        const unsigned short* f0p = feat0 + (size_t)node * 768 + li * 16;
        uint4 f0a = *(const uint4*)(f0p);
        uint4 f0b = *(const uint4*)(f0p + 8);
        float f0[16];
        unpack8(f0, f0a); unpack8(f0 + 8, f0b);
        unsigned short o[16];
        #pragma unroll
        for (int k = 0; k < 16; ++k)
            o[k] = f2bf(0.9f * acc[k] * wnorm + 0.1f * f0[k]);
        uint4* dst4 = (uint4*)(fout + (size_t)node * FDIM + li * 16);
        dst4[0] = *(uint4*)(o);
        dst4[1] = *(uint4*)(o + 8);
    }
}

// ---------------------------------------------------------------------------
extern "C" void kernel_launch(void* const* d_in, const int* in_sizes, int n_in,
                              void* d_out, int out_size, void* d_ws, size_t ws_size,
                              hipStream_t stream)
{
    const float* ent_feat = (const float*)d_in[0];
    const float* rel_feat = (const float*)d_in[1];
    const float* W_head   = (const float*)d_in[2];
    const float* W_tail   = (const float*)d_in[3];
    const float* W_ent    = (const float*)d_in[4];
    const float* W_rel    = (const float*)d_in[5];
    const float* attn     = (const float*)d_in[6];
    const float* ln_ent_g = (const float*)d_in[7];
    const float* ln_ent_b = (const float*)d_in[8];
    const float* ln_rel_g = (const float*)d_in[9];
    const float* ln_rel_b = (const float*)d_in[10];
    const float* ln_ff_g  = (const float*)d_in[11];
    const float* ln_ff_b  = (const float*)d_in[12];
    const float* W1       = (const float*)d_in[13];
    const float* b1       = (const float*)d_in[14];
    const float* W2       = (const float*)d_in[15];
    const float* b2       = (const float*)d_in[16];
    const int*   src      = (const int*)d_in[17];
    const int*   dst      = (const int*)d_in[18];
    const int*   rid      = (const int*)d_in[19];
    float* out = (float*)d_out;

    // ---- workspace carve (bytes, 256-aligned) ----
    char* base = (char*)d_ws;
    auto carve = [&](size_t bytes) { char* p = base; base += (bytes + 255) & ~(size_t)255; return p; };
    unsigned short* xb    = (unsigned short*)carve((size_t)N_NODES * FDIM * 2);
    unsigned short* projb = (unsigned short*)carve((size_t)N_NODES * 768 * 2);
    unsigned short* rlnb  = (unsigned short*)carve((size_t)N_REL * FDIM * 2);
    unsigned short* frelb = (unsigned short*)carve((size_t)N_REL * FDIM * 2);
    unsigned short* WtP   = (unsigned short*)carve((size_t)768 * FDIM * 2);
    unsigned short* WtR   = (unsigned short*)carve((size_t)FDIM * FDIM * 2);
    unsigned short* W1t   = (unsigned short*)carve((size_t)1024 * FDIM * 2);
    unsigned short* W2t   = (unsigned short*)carve((size_t)FDIM * 1024 * 2);
    unsigned short* hb0   = (unsigned short*)carve((size_t)N_NODES * FDIM * 2);
    unsigned short* hb1   = (unsigned short*)carve((size_t)N_NODES * FDIM * 2);
    unsigned short* yb    = (unsigned short*)carve((size_t)N_NODES * FDIM * 2);
    unsigned short* t1b   = (unsigned short*)carve((size_t)N_NODES * 1024 * 2);
    float* rst     = (float*)carve((size_t)N_NODES * FDIM * 4);
    float* csr_a   = (float*)carve(((size_t)N_EDGES * NHEAD + 256) * 4);
    float* invd    = (float*)carve((size_t)N_NODES * NHEAD * 4);
    int*   csr_src = (int*)carve((size_t)(N_EDGES + 64) * 4);
    int*   csr_rid = (int*)carve((size_t)(N_EDGES + 64) * 4);
    int*   deg     = (int*)carve((size_t)N_NODES * 4);
    float* logdeg  = (float*)carve((size_t)N_NODES * 4);
    int*   offsets = (int*)carve((size_t)(N_NODES + 1) * 4);
    int*   cursor  = (int*)carve((size_t)N_NODES * 4);
    int*   bsum    = (int*)carve((size_t)SCAN_BLOCKS * 4);

    hipMemsetAsync(deg, 0, (size_t)N_NODES * 4, stream);

    // fused LN -> bf16 (node + rel rows in one grid)
    ln_fused_kernel<<<N_NODES + N_REL, 64, 0, stream>>>(
        ent_feat, rel_feat, ln_ent_g, ln_ent_b, ln_rel_g, ln_rel_b, xb, rlnb);

    // fused weight transposes (6 matrices, 1 dispatch)
    transpose_all_kernel<<<786432 / 256, 256, 0, stream>>>(
        W_head, W_tail, W_ent, W_rel, W1, W2, WtP, WtR, W1t, W2t);

    // fused projection GEMM: proj[N,768] = xb @ [Wh|Wt|We]  (bf16 out, K=256)
    dim3 gproj((N_NODES + 127) / 128, 768 / 128);
    mfma_gemm_k256<<<gproj, 256, 0, stream>>>(xb, WtP, nullptr, projb,
                                              N_NODES, 768, 0);
    dim3 grel(1, FDIM / 128);
    mfma_gemm_k256<<<grel, 256, 0, stream>>>(rlnb, WtR, nullptr, frelb,
                                             N_REL, FDIM, 0);

    // CSR build (count -> 3-phase parallel scan -> scatter)
    count_kernel<<<(N_EDGES + 255) / 256, 256, 0, stream>>>(dst, deg, N_EDGES);
    scan1_kernel<<<SCAN_BLOCKS, 256, 0, stream>>>(deg, offsets, bsum, N_NODES);
    scan2_kernel<<<1, 128, 0, stream>>>(bsum, SCAN_BLOCKS);
    scan3_kernel<<<SCAN_BLOCKS, 256, 0, stream>>>(deg, offsets, bsum, cursor, logdeg,
                                                  N_NODES, N_EDGES);
    scatter_kernel<<<(N_EDGES + 255) / 256, 256, 0, stream>>>(dst, src, rid, cursor,
                                                              csr_src, csr_rid, N_EDGES);

    // attention scores (unnormalized exp) + per-(node,head) 1/denom
    edge_score_csr_kernel<<<(N_NODES + 3) / 4, 256, 0, stream>>>(
        projb, frelb, attn, csr_src, csr_rid, offsets, logdeg, csr_a, invd, N_NODES);

    // 5-hop PPR diffusion (bf16): fen(proj+512) -> hb0 -> hb1 -> hb0 -> hb1 -> hb0
    const unsigned short* fen = projb + 512;
    int gdif = (N_NODES + 3) / 4;
    diffuse_kernel<<<gdif, 256, 0, stream>>>(fen, 768, fen, csr_a, invd, csr_src, offsets, hb0, N_NODES);
    diffuse_kernel<<<gdif, 256, 0, stream>>>(hb0, FDIM, fen, csr_a, invd, csr_src, offsets, hb1, N_NODES);
    diffuse_kernel<<<gdif, 256, 0, stream>>>(hb1, FDIM, fen, csr_a, invd, csr_src, offsets, hb0, N_NODES);
    diffuse_kernel<<<gdif, 256, 0, stream>>>(hb0, FDIM, fen, csr_a, invd, csr_src, offsets, hb1, N_NODES);
    diffuse_kernel<<<gdif, 256, 0, stream>>>(hb1, FDIM, fen, csr_a, invd, csr_src, offsets, hb0, N_NODES);

    // residual + pre-LN
    rst_ln_kernel<<<N_NODES, 64, 0, stream>>>(hb0, ent_feat, ln_ff_g, ln_ff_b, rst, yb);

    // FFN1: t1 = relu(y@W1 + b1) [bf16], K=256 single-stage
    dim3 gff1((N_NODES + 127) / 128, 1024 / 128);
    mfma_gemm_k256<<<gff1, 256, 0, stream>>>(yb, W1t, b1, t1b,
                                             N_NODES, 1024, 1);
    // FFN2: out = t1@W2 + b2 + rst, 64x128 tiles (K=1024, dbuf)
    dim3 gff2((N_NODES + 63) / 64, FDIM / 128);
    mfma_gemm64_bt<<<gff2, 256, 0, stream>>>(t1b, W2t, b2, rst, out,
                                             N_NODES, 1024, FDIM);
}

// Round 9
// 460.121 us; speedup vs baseline: 1.0741x; 1.0741x over previous
//
#include <hip/hip_runtime.h>

#define N_NODES 20000
#define N_EDGES 320000
#define N_REL   100
#define FDIM    256
#define NHEAD   8
#define HDIM    32
#define SCAN_BLOCKS ((N_NODES + 255) / 256)   // 79

using short8 = __attribute__((ext_vector_type(8))) short;   // 8 bf16 in 4 VGPRs
using f32x4  = __attribute__((ext_vector_type(4))) float;

__device__ inline unsigned short f2bf(float f) {
    union { float f; unsigned int u; } v; v.f = f;
    unsigned int r = v.u + 0x7fff + ((v.u >> 16) & 1);   // RNE
    return (unsigned short)(r >> 16);
}
__device__ inline float bf2f(unsigned short u) {
    union { unsigned int i; float f; } v; v.i = ((unsigned int)u) << 16; return v.f;
}
__device__ inline float4 bf4(ushort4 u) {
    return make_float4(bf2f(u.x), bf2f(u.y), bf2f(u.z), bf2f(u.w));
}
// unpack 8 bf16 (uint4) -> 8 fp32
__device__ inline void unpack8(float* d, uint4 u) {
    union { unsigned int u; float f; } t;
    t.u = u.x << 16;         d[0] = t.f;
    t.u = u.x & 0xffff0000u; d[1] = t.f;
    t.u = u.y << 16;         d[2] = t.f;
    t.u = u.y & 0xffff0000u; d[3] = t.f;
    t.u = u.z << 16;         d[4] = t.f;
    t.u = u.z & 0xffff0000u; d[5] = t.f;
    t.u = u.w << 16;         d[6] = t.f;
    t.u = u.w & 0xffff0000u; d[7] = t.f;
}
// acc[k] += w * bf16(u)[k], 8 elements
__device__ inline void fma8(float* acc, uint4 u, float w) {
    union { unsigned int u; float f; } t;
    t.u = u.x << 16;         acc[0] += w * t.f;
    t.u = u.x & 0xffff0000u; acc[1] += w * t.f;
    t.u = u.y << 16;         acc[2] += w * t.f;
    t.u = u.y & 0xffff0000u; acc[3] += w * t.f;
    t.u = u.z << 16;         acc[4] += w * t.f;
    t.u = u.z & 0xffff0000u; acc[5] += w * t.f;
    t.u = u.w << 16;         acc[6] += w * t.f;
    t.u = u.w & 0xffff0000u; acc[7] += w * t.f;
}
// direct global -> LDS DMA, 16 bytes per lane (gfx950 global_load_lds_dwordx4)
__device__ __forceinline__ void g2lds16(const unsigned short* g, unsigned short* l) {
    __builtin_amdgcn_global_load_lds(
        (const __attribute__((address_space(1))) unsigned int*)g,
        (__attribute__((address_space(3))) unsigned int*)l,
        16, 0, 0);
}

// bijective XCD swizzle (m204)
__device__ inline void xcd_tile(int* m0, int* n0, int tm, int tn) {
    int nwg  = gridDim.x * gridDim.y;
    int wgid = blockIdx.x + blockIdx.y * gridDim.x;
    int q = nwg >> 3, r = nwg & 7;
    int xcd = wgid & 7, pos = wgid >> 3;
    int nid = (xcd < r ? xcd * (q + 1) : r * (q + 1) + (xcd - r) * q) + pos;
    int gy = gridDim.y;
    int bx = nid / gy;
    int by = nid - bx * gy;
    *m0 = bx * tm;
    *n0 = by * tn;
}

// ---------------------------------------------------------------------------
// Fused LayerNorm (node rows + rel rows in one grid) -> bf16. One wave/row.
// ---------------------------------------------------------------------------
__global__ __launch_bounds__(64) void ln_fused_kernel(
    const float* __restrict__ ent, const float* __restrict__ rel,
    const float* __restrict__ ge, const float* __restrict__ be,
    const float* __restrict__ gr, const float* __restrict__ br,
    unsigned short* __restrict__ xb, unsigned short* __restrict__ rlnb)
{
    int row = blockIdx.x;
    const float *in, *g, *b; unsigned short* out; int r;
    if (row < N_NODES) { in = ent; g = ge; b = be; out = xb;   r = row; }
    else               { in = rel; g = gr; b = br; out = rlnb; r = row - N_NODES; }
    int tid = threadIdx.x;
    const float4 v = *(const float4*)(in + (size_t)r * FDIM + tid * 4);
    float s = v.x + v.y + v.z + v.w;
    float q = v.x * v.x + v.y * v.y + v.z * v.z + v.w * v.w;
    #pragma unroll
    for (int d = 1; d < 64; d <<= 1) { s += __shfl_xor(s, d); q += __shfl_xor(q, d); }
    float mean = s * (1.0f / FDIM);
    float var  = q * (1.0f / FDIM) - mean * mean;
    float inv  = rsqrtf(var + 1e-5f);
    float4 gg = *(const float4*)(g + tid * 4);
    float4 bb = *(const float4*)(b + tid * 4);
    ushort4 o;
    o.x = f2bf((v.x - mean) * inv * gg.x + bb.x);
    o.y = f2bf((v.y - mean) * inv * gg.y + bb.y);
    o.z = f2bf((v.z - mean) * inv * gg.z + bb.z);
    o.w = f2bf((v.w - mean) * inv * gg.w + bb.w);
    *(ushort4*)(out + (size_t)r * FDIM + tid * 4) = o;
}

// rst = bf2f(feat) + ent (fp32) ; y = LN(rst) (bf16)
__global__ __launch_bounds__(64) void rst_ln_kernel(
    const unsigned short* __restrict__ feat, const float* __restrict__ ent,
    const float* __restrict__ g, const float* __restrict__ b,
    float* __restrict__ rst, unsigned short* __restrict__ y)
{
    int row = blockIdx.x;
    int tid = threadIdx.x;
    const float4 f = bf4(*(const ushort4*)(feat + (size_t)row * FDIM + tid * 4));
    const float4 e = *(const float4*)(ent + (size_t)row * FDIM + tid * 4);
    float4 r;
    r.x = f.x + e.x; r.y = f.y + e.y; r.z = f.z + e.z; r.w = f.w + e.w;
    *(float4*)(rst + (size_t)row * FDIM + tid * 4) = r;
    float s = r.x + r.y + r.z + r.w;
    float q = r.x * r.x + r.y * r.y + r.z * r.z + r.w * r.w;
    #pragma unroll
    for (int d = 1; d < 64; d <<= 1) { s += __shfl_xor(s, d); q += __shfl_xor(q, d); }
    float mean = s * (1.0f / FDIM);
    float var  = q * (1.0f / FDIM) - mean * mean;
    float inv  = rsqrtf(var + 1e-5f);
    float4 gg = *(const float4*)(g + tid * 4);
    float4 bb = *(const float4*)(b + tid * 4);
    ushort4 o;
    o.x = f2bf((r.x - mean) * inv * gg.x + bb.x);
    o.y = f2bf((r.y - mean) * inv * gg.y + bb.y);
    o.z = f2bf((r.z - mean) * inv * gg.z + bb.z);
    o.w = f2bf((r.w - mean) * inv * gg.w + bb.w);
    *(ushort4*)(y + (size_t)row * FDIM + tid * 4) = o;
}

// ---------------------------------------------------------------------------
// Fused weight transposes: all 6 fp32[K,N] -> bf16[N,K] in one dispatch.
// ---------------------------------------------------------------------------
__global__ void transpose_all_kernel(
    const float* __restrict__ Wh, const float* __restrict__ Wt_,
    const float* __restrict__ We, const float* __restrict__ Wr,
    const float* __restrict__ W1, const float* __restrict__ W2,
    unsigned short* __restrict__ WtP, unsigned short* __restrict__ WtR,
    unsigned short* __restrict__ W1t, unsigned short* __restrict__ W2t)
{
    int idx = blockIdx.x * 256 + threadIdx.x;
    if (idx < 196608) {
        int seg = idx >> 16, r = idx & 65535;
        const float* W = (seg == 0) ? Wh : (seg == 1) ? Wt_ : We;
        int n = r >> 8, k = r & 255;
        WtP[idx] = f2bf(W[k * 256 + n]);
    } else if (idx < 262144) {
        int r = idx - 196608;
        int n = r >> 8, k = r & 255;
        WtR[r] = f2bf(Wr[k * 256 + n]);
    } else if (idx < 524288) {
        int r = idx - 262144;                 // K=256, N=1024
        int n = r >> 8, k = r & 255;
        W1t[r] = f2bf(W1[k * 1024 + n]);
    } else if (idx < 786432) {
        int r = idx - 524288;                 // K=1024, N=256
        int n = r >> 10, k = r & 1023;
        W2t[r] = f2bf(W2[k * 256 + n]);
    }
}

// ---------------------------------------------------------------------------
// bf16 MFMA GEMM (B^T): C[M,N] = A[M,K] @ Bt[N,K]^T  (+bias)(relu)(+add)
// 128x128 tile, 4 waves, 4x4 16x16x32 frags/wave, BK=32.
// Double-buffered LDS + single barrier per K-step + XCD-aware swizzle.
// (r8's k256 single-stage variant was duration-neutral — reverted.)
// ---------------------------------------------------------------------------
__global__ __launch_bounds__(256) void mfma_gemm_bt(
    const unsigned short* __restrict__ A, const unsigned short* __restrict__ Bt,
    const float* __restrict__ bias, const float* __restrict__ add,
    float* __restrict__ Cf, unsigned short* __restrict__ Cb,
    int M, int K, int N, int relu)
{
    __shared__ unsigned short As[2][128 * 32];
    __shared__ unsigned short Bs[2][128 * 32];
    int tid  = threadIdx.x;
    int wave = tid >> 6, lane = tid & 63;
    int quad = lane >> 4, l16 = lane & 15;
    int m0, n0;
    xcd_tile(&m0, &n0, 128, 128);
    int wr = (wave >> 1) * 64, wc = (wave & 1) * 64;

    f32x4 acc[4][4] = {};

    int cA = tid, cB = tid + 256;
    int rA0 = cA >> 2, kA0 = (cA & 3) * 8;
    int rB0 = cB >> 2, kB0 = (cB & 3) * 8;
    int rA = m0 + rA0; if (rA >= M) rA = M - 1;
    int rB = m0 + rB0; if (rB >= M) rB = M - 1;
    const unsigned short* gA0 = A + (size_t)rA * K + kA0;
    const unsigned short* gA1 = A + (size_t)rB * K + kB0;
    const unsigned short* gB0 = Bt + (size_t)(n0 + rA0) * K + kA0;
    const unsigned short* gB1 = Bt + (size_t)(n0 + rB0) * K + kB0;

    g2lds16(gA0, As[0] + cA * 8);
    g2lds16(gA1, As[0] + cB * 8);
    g2lds16(gB0, Bs[0] + cA * 8);
    g2lds16(gB1, Bs[0] + cB * 8);
    __syncthreads();

    int cur = 0;
    for (int k0 = 0; k0 < K; k0 += 32) {
        int k1 = k0 + 32;
        if (k1 < K) {
            int nb = cur ^ 1;
            g2lds16(gA0 + k1, As[nb] + cA * 8);
            g2lds16(gA1 + k1, As[nb] + cB * 8);
            g2lds16(gB0 + k1, Bs[nb] + cA * 8);
            g2lds16(gB1 + k1, Bs[nb] + cB * 8);
        }
        short8 af[4], bfr[4];
        #pragma unroll
        for (int i = 0; i < 4; ++i)
            af[i] = *(const short8*)(As[cur] + (wr + i * 16 + l16) * 32 + quad * 8);
        #pragma unroll
        for (int j = 0; j < 4; ++j)
            bfr[j] = *(const short8*)(Bs[cur] + (wc + j * 16 + l16) * 32 + quad * 8);
        #pragma unroll
        for (int i = 0; i < 4; ++i)
            #pragma unroll
            for (int j = 0; j < 4; ++j)
                acc[i][j] = __builtin_amdgcn_mfma_f32_16x16x32_bf16(
                    af[i], bfr[j], acc[i][j], 0, 0, 0);
        __syncthreads();
        cur ^= 1;
    }

    #pragma unroll
    for (int i = 0; i < 4; ++i) {
        #pragma unroll
        for (int j = 0; j < 4; ++j) {
            int col = n0 + wc + j * 16 + l16;
            float bsv = bias ? bias[col] : 0.0f;
            #pragma unroll
            for (int r = 0; r < 4; ++r) {
                int row = m0 + wr + i * 16 + quad * 4 + r;
                if (row < M) {
                    float v = acc[i][j][r] + bsv;
                    if (relu) v = fmaxf(v, 0.0f);
                    if (add)  v += add[(size_t)row * N + col];
                    if (Cf) Cf[(size_t)row * N + col] = v;
                    else    Cb[(size_t)row * N + col] = f2bf(v);
                }
            }
        }
    }
}

// ---------------------------------------------------------------------------
// 64x128-tile variant (small grids / long K, e.g. FFN2): 4 waves, 4x2 frags.
// ---------------------------------------------------------------------------
__global__ __launch_bounds__(256) void mfma_gemm64_bt(
    const unsigned short* __restrict__ A, const unsigned short* __restrict__ Bt,
    const float* __restrict__ bias, const float* __restrict__ add,
    float* __restrict__ Cf, int M, int K, int N)
{
    __shared__ unsigned short As[2][64 * 32];
    __shared__ unsigned short Bs[2][128 * 32];
    int tid  = threadIdx.x;
    int wave = tid >> 6, lane = tid & 63;
    int quad = lane >> 4, l16 = lane & 15;
    int m0, n0;
    xcd_tile(&m0, &n0, 64, 128);
    int wc = wave * 32;

    f32x4 acc[4][2] = {};

    int rA0 = tid >> 2, kA0 = (tid & 3) * 8;
    int cB0 = tid, cB1 = tid + 256;
    int rB0 = cB0 >> 2, kB0 = (cB0 & 3) * 8;
    int rB1 = cB1 >> 2, kB1 = (cB1 & 3) * 8;
    int rA = m0 + rA0; if (rA >= M) rA = M - 1;
    const unsigned short* gA  = A + (size_t)rA * K + kA0;
    const unsigned short* gB0 = Bt + (size_t)(n0 + rB0) * K + kB0;
    const unsigned short* gB1 = Bt + (size_t)(n0 + rB1) * K + kB1;

    g2lds16(gA,  As[0] + tid * 8);
    g2lds16(gB0, Bs[0] + cB0 * 8);
    g2lds16(gB1, Bs[0] + cB1 * 8);
    __syncthreads();

    int cur = 0;
    for (int k0 = 0; k0 < K; k0 += 32) {
        short8 af[4], bfr[2];
        #pragma unroll
        for (int i = 0; i < 4; ++i)
            af[i] = *(const short8*)(As[cur] + (i * 16 + l16) * 32 + quad * 8);
        #pragma unroll
        for (int j = 0; j < 2; ++j)
            bfr[j] = *(const short8*)(Bs[cur] + (wc + j * 16 + l16) * 32 + quad * 8);
        int k1 = k0 + 32;
        if (k1 < K) {
            int nb = cur ^ 1;
            g2lds16(gA + k1,  As[nb] + tid * 8);
            g2lds16(gB0 + k1, Bs[nb] + cB0 * 8);
            g2lds16(gB1 + k1, Bs[nb] + cB1 * 8);
        }
        #pragma unroll
        for (int i = 0; i < 4; ++i)
            #pragma unroll
            for (int j = 0; j < 2; ++j)
                acc[i][j] = __builtin_amdgcn_mfma_f32_16x16x32_bf16(
                    af[i], bfr[j], acc[i][j], 0, 0, 0);
        __syncthreads();
        cur ^= 1;
    }

    #pragma unroll
    for (int i = 0; i < 4; ++i) {
        #pragma unroll
        for (int j = 0; j < 2; ++j) {
            int col = n0 + wc + j * 16 + l16;
            float bsv = bias ? bias[col] : 0.0f;
            #pragma unroll
            for (int r = 0; r < 4; ++r) {
                int row = m0 + i * 16 + quad * 4 + r;
                if (row < M) {
                    float v = acc[i][j][r] + bsv;
                    if (add) v += add[(size_t)row * N + col];
                    Cf[(size_t)row * N + col] = v;
                }
            }
        }
    }
}

// ---------------------------------------------------------------------------
// Graph plumbing: degree count -> 3-phase parallel scan -> scatter
// ---------------------------------------------------------------------------
__global__ void count_kernel(const int* __restrict__ dst, int* __restrict__ deg, int E)
{
    int i = blockIdx.x * blockDim.x + threadIdx.x;
    if (i < E) atomicAdd(&deg[dst[i]], 1);
}

__global__ __launch_bounds__(256) void scan1_kernel(
    const int* __restrict__ deg, int* __restrict__ offsets, int* __restrict__ bsum, int n)
{
    __shared__ int tmp[256];
    int tid = threadIdx.x;
    int i = blockIdx.x * 256 + tid;
    int v = (i < n) ? deg[i] : 0;
    tmp[tid] = v;
    __syncthreads();
    for (int d = 1; d < 256; d <<= 1) {
        int u = (tid >= d) ? tmp[tid - d] : 0;
        __syncthreads();
        tmp[tid] += u;
        __syncthreads();
    }
    if (i < n) offsets[i] = tmp[tid] - v;
    if (tid == 255) bsum[blockIdx.x] = tmp[255];
}

__global__ __launch_bounds__(128) void scan2_kernel(int* __restrict__ bsum, int nb)
{
    __shared__ int tmp[128];
    int tid = threadIdx.x;
    int v = (tid < nb) ? bsum[tid] : 0;
    tmp[tid] = v;
    __syncthreads();
    for (int d = 1; d < 128; d <<= 1) {
        int u = (tid >= d) ? tmp[tid - d] : 0;
        __syncthreads();
        tmp[tid] += u;
        __syncthreads();
    }
    if (tid < nb) bsum[tid] = tmp[tid] - v;
}

__global__ __launch_bounds__(256) void scan3_kernel(
    const int* __restrict__ deg, int* __restrict__ offsets,
    const int* __restrict__ bsum, int* __restrict__ cursor,
    float* __restrict__ logdeg, int n, int E)
{
    int i = blockIdx.x * 256 + threadIdx.x;
    if (i < n) {
        int o = offsets[i] + bsum[blockIdx.x];
        offsets[i] = o;
        cursor[i]  = o;
        logdeg[i]  = logf((float)deg[i]);
    }
    if (i == 0) offsets[n] = E;
}

__global__ void scatter_kernel(const int* __restrict__ dst, const int* __restrict__ src,
                               const int* __restrict__ rid, int* __restrict__ cursor,
                               int* __restrict__ csr_src, int* __restrict__ csr_rid, int E)
{
    int i = blockIdx.x * blockDim.x + threadIdx.x;
    if (i < E) {
        int p = atomicAdd(&cursor[dst[i]], 1);
        csr_src[p] = src[i];
        csr_rid[p] = rid[i];
    }
}

// ---------------------------------------------------------------------------
// FUSED edge attention + PPR hop 1. One wave per dst node (4/block);
// 16 lanes per edge, 4 edges in flight. Per edge: gather fh row (+0) and
// fen row (+1024B) of the SAME proj row + frel row; compute 8 head scores,
// ex = exp(score*scale); accumulate acc += ex * fen (unnormalized) and
// denom += ex; normalize once at the end (identical math to r7's invd
// scheme). Writes ex to csr_a + 1/denom to invd for hops 2-5, and the
// hop-1 output to fout. Saves one full kernel pass (launch + index/tv
// reload + 10 MB csr_a re-read) vs separate edge_score + diffuse.
// ---------------------------------------------------------------------------
__global__ __launch_bounds__(256) void score_hop1_kernel(
    const unsigned short* __restrict__ proj,   // [N,768]: fh | ftl | fen
    const unsigned short* __restrict__ frel,   // [R,256] bf16
    const float* __restrict__ attn,
    const int* __restrict__ csr_src, const int* __restrict__ csr_rid,
    const int* __restrict__ offsets, const float* __restrict__ logdeg,
    float* __restrict__ csr_a, float* __restrict__ invd,
    unsigned short* __restrict__ fout, int n)
{
    int node = blockIdx.x * 4 + (threadIdx.x >> 6);
    if (node >= n) return;
    int tid = threadIdx.x & 63;
    int g = tid >> 4, li = tid & 15;
    int start = offsets[node], end = offsets[node + 1];
    float scale = logdeg[node] * (1.0f / 32.0f);

    float tv[16], at[16];
    {
        const unsigned short* tp = proj + (size_t)node * 768 + 256 + li * 16;
        uint4 a0 = *(const uint4*)tp, a1 = *(const uint4*)(tp + 8);
        unpack8(tv, a0); unpack8(tv + 8, a1);
        const float4* ap = (const float4*)(attn + li * 16);
        float4 f;
        f = ap[0]; at[0] = f.x; at[1] = f.y; at[2]  = f.z; at[3]  = f.w;
        f = ap[1]; at[4] = f.x; at[5] = f.y; at[6]  = f.z; at[7]  = f.w;
        f = ap[2]; at[8] = f.x; at[9] = f.y; at[10] = f.z; at[11] = f.w;
        f = ap[3]; at[12] = f.x; at[13] = f.y; at[14] = f.z; at[15] = f.w;
    }

    float acc[16] = {};
    float denom = 0.f;
    for (int p = start; p < end; p += 4) {
        int e = p + g;
        bool va = e < end;
        int q = va ? e : end - 1;
        int s = csr_src[q], r = csr_rid[q];
        const unsigned short* hp = proj + (size_t)s * 768 + li * 16;
        const unsigned short* rp = frel + (size_t)r * FDIM + li * 16;
        uint4 h0 = *(const uint4*)hp,        h1 = *(const uint4*)(hp + 8);
        uint4 r0 = *(const uint4*)rp,        r1 = *(const uint4*)(rp + 8);
        uint4 e0 = *(const uint4*)(hp + 512), e1 = *(const uint4*)(hp + 520);
        float hv[16], rv[16];
        unpack8(hv, h0); unpack8(hv + 8, h1);
        unpack8(rv, r0); unpack8(rv + 8, r1);
        float sum = 0.f;
        #pragma unroll
        for (int k = 0; k < 16; ++k) {
            float m = hv[k] * tv[k] * rv[k];
            m = (m > 0.f) ? m : 0.2f * m;
            sum += m * at[k];
        }
        sum += __shfl_xor(sum, 1);               // both lanes of pair: head sum
        float ex = va ? __expf(sum * scale) : 0.f;
        if (va && ((li & 1) == 0))
            csr_a[(size_t)e * NHEAD + (li >> 1)] = ex;
        denom += ex;                             // per-lane: its head's partial
        fma8(acc + 0, e0, ex);                   // unnormalized weighted fen
        fma8(acc + 8, e1, ex);
    }
    // cross-group reduce (groups at lane strides 16/32)
    denom += __shfl_xor(denom, 16);
    denom += __shfl_xor(denom, 32);
    #pragma unroll
    for (int k = 0; k < 16; ++k) {
        acc[k] += __shfl_xor(acc[k], 16);
        acc[k] += __shfl_xor(acc[k], 32);
    }
    float wn = 1.0f / denom;                     // this lane's head denom
    if (g == 0 && (li & 1) == 0)
        invd[node * NHEAD + (li >> 1)] = wn;
    if (g == 0) {
        const unsigned short* f0p = proj + (size_t)node * 768 + 512 + li * 16;
        uint4 f0a = *(const uint4*)(f0p);
        uint4 f0b = *(const uint4*)(f0p + 8);
        float f0[16];
        unpack8(f0, f0a); unpack8(f0 + 8, f0b);
        unsigned short o[16];
        #pragma unroll
        for (int k = 0; k < 16; ++k)
            o[k] = f2bf(0.9f * acc[k] * wn + 0.1f * f0[k]);
        uint4* dst4 = (uint4*)(fout + (size_t)node * FDIM + li * 16);
        dst4[0] = *(uint4*)(o);
        dst4[1] = *(uint4*)(o + 8);
    }
}

// ---------------------------------------------------------------------------
// One PPR hop (bf16) — r1-proven structure. One wave per dst node (4/block);
// 16 lanes per edge, 16 edges in flight; cross-group reduce once/node.
// ---------------------------------------------------------------------------
__global__ __launch_bounds__(256) void diffuse_kernel(
    const unsigned short* __restrict__ fin, int fin_stride,
    const unsigned short* __restrict__ feat0,   // stride 768 (fen in proj)
    const float* __restrict__ a, const float* __restrict__ invd,
    const int* __restrict__ csr_src,
    const int* __restrict__ offsets, unsigned short* __restrict__ fout, int n)
{
    int node = blockIdx.x * 4 + (threadIdx.x >> 6);
    if (node >= n) return;
    int tid = threadIdx.x & 63;
    int g = tid >> 4, li = tid & 15;
    int hh = li >> 1;
    int start = offsets[node], end = offsets[node + 1];
    float wnorm = invd[node * NHEAD + hh];
    float acc[16] = {};

    for (int p = start; p < end; p += 16) {
        uint4 u0[4], u1[4]; float w[4];
        #pragma unroll
        for (int t = 0; t < 4; ++t) {
            int pe = p + t * 4 + g;
            int q = (pe < end) ? pe : end - 1;
            int s = csr_src[q];
            w[t] = (pe < end) ? a[(size_t)q * NHEAD + hh] : 0.0f;
            const unsigned short* rp = fin + (size_t)s * fin_stride + li * 16;
            u0[t] = *(const uint4*)(rp);
            u1[t] = *(const uint4*)(rp + 8);
        }
        #pragma unroll
        for (int t = 0; t < 4; ++t) {
            fma8(acc + 0, u0[t], w[t]);
            fma8(acc + 8, u1[t], w[t]);
        }
    }
    #pragma unroll
    for (int k = 0; k < 16; ++k) {
        acc[k] += __shfl_xor(acc[k], 16);
        acc[k] += __shfl_xor(acc[k], 32);
    }
    if (g == 0) {
        const unsigned short* f0p = feat0 + (size_t)node * 768 + li * 16;
        uint4 f0a = *(const uint4*)(f0p);
        uint4 f0b = *(const uint4*)(f0p + 8);
        float f0[16];
        unpack8(f0, f0a); unpack8(f0 + 8, f0b);
        unsigned short o[16];
        #pragma unroll
        for (int k = 0; k < 16; ++k)
            o[k] = f2bf(0.9f * acc[k] * wnorm + 0.1f * f0[k]);
        uint4* dst4 = (uint4*)(fout + (size_t)node * FDIM + li * 16);
        dst4[0] = *(uint4*)(o);
        dst4[1] = *(uint4*)(o + 8);
    }
}

// ---------------------------------------------------------------------------
extern "C" void kernel_launch(void* const* d_in, const int* in_sizes, int n_in,
                              void* d_out, int out_size, void* d_ws, size_t ws_size,
                              hipStream_t stream)
{
    const float* ent_feat = (const float*)d_in[0];
    const float* rel_feat = (const float*)d_in[1];
    const float* W_head   = (const float*)d_in[2];
    const float* W_tail   = (const float*)d_in[3];
    const float* W_ent    = (const float*)d_in[4];
    const float* W_rel    = (const float*)d_in[5];
    const float* attn     = (const float*)d_in[6];
    const float* ln_ent_g = (const float*)d_in[7];
    const float* ln_ent_b = (const float*)d_in[8];
    const float* ln_rel_g = (const float*)d_in[9];
    const float* ln_rel_b = (const float*)d_in[10];
    const float* ln_ff_g  = (const float*)d_in[11];
    const float* ln_ff_b  = (const float*)d_in[12];
    const float* W1       = (const float*)d_in[13];
    const float* b1       = (const float*)d_in[14];
    const float* W2       = (const float*)d_in[15];
    const float* b2       = (const float*)d_in[16];
    const int*   src      = (const int*)d_in[17];
    const int*   dst      = (const int*)d_in[18];
    const int*   rid      = (const int*)d_in[19];
    float* out = (float*)d_out;

    // ---- workspace carve (bytes, 256-aligned) ----
    char* base = (char*)d_ws;
    auto carve = [&](size_t bytes) { char* p = base; base += (bytes + 255) & ~(size_t)255; return p; };
    unsigned short* xb    = (unsigned short*)carve((size_t)N_NODES * FDIM * 2);
    unsigned short* projb = (unsigned short*)carve((size_t)N_NODES * 768 * 2);
    unsigned short* rlnb  = (unsigned short*)carve((size_t)N_REL * FDIM * 2);
    unsigned short* frelb = (unsigned short*)carve((size_t)N_REL * FDIM * 2);
    unsigned short* WtP   = (unsigned short*)carve((size_t)768 * FDIM * 2);
    unsigned short* WtR   = (unsigned short*)carve((size_t)FDIM * FDIM * 2);
    unsigned short* W1t   = (unsigned short*)carve((size_t)1024 * FDIM * 2);
    unsigned short* W2t   = (unsigned short*)carve((size_t)FDIM * 1024 * 2);
    unsigned short* hb0   = (unsigned short*)carve((size_t)N_NODES * FDIM * 2);
    unsigned short* hb1   = (unsigned short*)carve((size_t)N_NODES * FDIM * 2);
    unsigned short* yb    = (unsigned short*)carve((size_t)N_NODES * FDIM * 2);
    unsigned short* t1b   = (unsigned short*)carve((size_t)N_NODES * 1024 * 2);
    float* rst     = (float*)carve((size_t)N_NODES * FDIM * 4);
    float* csr_a   = (float*)carve(((size_t)N_EDGES * NHEAD + 256) * 4);
    float* invd    = (float*)carve((size_t)N_NODES * NHEAD * 4);
    int*   csr_src = (int*)carve((size_t)(N_EDGES + 64) * 4);
    int*   csr_rid = (int*)carve((size_t)(N_EDGES + 64) * 4);
    int*   deg     = (int*)carve((size_t)N_NODES * 4);
    float* logdeg  = (float*)carve((size_t)N_NODES * 4);
    int*   offsets = (int*)carve((size_t)(N_NODES + 1) * 4);
    int*   cursor  = (int*)carve((size_t)N_NODES * 4);
    int*   bsum    = (int*)carve((size_t)SCAN_BLOCKS * 4);

    hipMemsetAsync(deg, 0, (size_t)N_NODES * 4, stream);

    // fused LN -> bf16 (node + rel rows in one grid)
    ln_fused_kernel<<<N_NODES + N_REL, 64, 0, stream>>>(
        ent_feat, rel_feat, ln_ent_g, ln_ent_b, ln_rel_g, ln_rel_b, xb, rlnb);

    // fused weight transposes (6 matrices, 1 dispatch)
    transpose_all_kernel<<<786432 / 256, 256, 0, stream>>>(
        W_head, W_tail, W_ent, W_rel, W1, W2, WtP, WtR, W1t, W2t);

    // fused projection GEMM: proj[N,768] = xb @ [Wh|Wt|We]  (bf16 out)
    dim3 gproj((N_NODES + 127) / 128, 768 / 128);
    mfma_gemm_bt<<<gproj, 256, 0, stream>>>(xb, WtP, nullptr, nullptr, nullptr, projb,
                                            N_NODES, FDIM, 768, 0);
    dim3 grel(1, FDIM / 128);
    mfma_gemm_bt<<<grel, 256, 0, stream>>>(rlnb, WtR, nullptr, nullptr, nullptr, frelb,
                                           N_REL, FDIM, FDIM, 0);

    // CSR build (count -> 3-phase parallel scan -> scatter)
    count_kernel<<<(N_EDGES + 255) / 256, 256, 0, stream>>>(dst, deg, N_EDGES);
    scan1_kernel<<<SCAN_BLOCKS, 256, 0, stream>>>(deg, offsets, bsum, N_NODES);
    scan2_kernel<<<1, 128, 0, stream>>>(bsum, SCAN_BLOCKS);
    scan3_kernel<<<SCAN_BLOCKS, 256, 0, stream>>>(deg, offsets, bsum, cursor, logdeg,
                                                  N_NODES, N_EDGES);
    scatter_kernel<<<(N_EDGES + 255) / 256, 256, 0, stream>>>(dst, src, rid, cursor,
                                                              csr_src, csr_rid, N_EDGES);

    // FUSED attention scores + hop 1 (writes csr_a, invd, hb0)
    score_hop1_kernel<<<(N_NODES + 3) / 4, 256, 0, stream>>>(
        projb, frelb, attn, csr_src, csr_rid, offsets, logdeg,
        csr_a, invd, hb0, N_NODES);

    // hops 2-5: hb0 -> hb1 -> hb0 -> hb1 -> hb0
    const unsigned short* fen = projb + 512;
    int gdif = (N_NODES + 3) / 4;
    diffuse_kernel<<<gdif, 256, 0, stream>>>(hb0, FDIM, fen, csr_a, invd, csr_src, offsets, hb1, N_NODES);
    diffuse_kernel<<<gdif, 256, 0, stream>>>(hb1, FDIM, fen, csr_a, invd, csr_src, offsets, hb0, N_NODES);
    diffuse_kernel<<<gdif, 256, 0, stream>>>(hb0, FDIM, fen, csr_a, invd, csr_src, offsets, hb1, N_NODES);
    diffuse_kernel<<<gdif, 256, 0, stream>>>(hb1, FDIM, fen, csr_a, invd, csr_src, offsets, hb0, N_NODES);

    // residual + pre-LN
    rst_ln_kernel<<<N_NODES, 64, 0, stream>>>(hb0, ent_feat, ln_ff_g, ln_ff_b, rst, yb);

    // FFN1: t1 = relu(y@W1 + b1) [bf16], 128x128 tiles
    dim3 gff1((N_NODES + 127) / 128, 1024 / 128);
    mfma_gemm_bt<<<gff1, 256, 0, stream>>>(yb, W1t, b1, nullptr, nullptr, t1b,
                                           N_NODES, FDIM, 1024, 1);
    // FFN2: out = t1@W2 + b2 + rst, 64x128 tiles
    dim3 gff2((N_NODES + 63) / 64, FDIM / 128);
    mfma_gemm64_bt<<<gff2, 256, 0, stream>>>(t1b, W2t, b2, rst, out,
                                             N_NODES, 1024, FDIM);
}

// Round 10
// 456.440 us; speedup vs baseline: 1.0827x; 1.0081x over previous
//
#include <hip/hip_runtime.h>

#define N_NODES 20000
#define N_EDGES 320000
#define N_REL   100
#define FDIM    256
#define NHEAD   8
#define HDIM    32
#define SCAN_BLOCKS ((N_NODES + 255) / 256)   // 79
#define LN_BLOCKS  ((N_NODES + N_REL) / 4)    // 5025
#define TR_BLOCKS  3072                        // 786432 / 256
#define CNT_BLOCKS ((N_EDGES + 255) / 256)     // 1250

using short8 = __attribute__((ext_vector_type(8))) short;   // 8 bf16 in 4 VGPRs
using f32x4  = __attribute__((ext_vector_type(4))) float;

__device__ inline unsigned short f2bf(float f) {
    union { float f; unsigned int u; } v; v.f = f;
    unsigned int r = v.u + 0x7fff + ((v.u >> 16) & 1);   // RNE
    return (unsigned short)(r >> 16);
}
__device__ inline float bf2f(unsigned short u) {
    union { unsigned int i; float f; } v; v.i = ((unsigned int)u) << 16; return v.f;
}
__device__ inline float4 bf4(ushort4 u) {
    return make_float4(bf2f(u.x), bf2f(u.y), bf2f(u.z), bf2f(u.w));
}
// unpack 8 bf16 (uint4) -> 8 fp32
__device__ inline void unpack8(float* d, uint4 u) {
    union { unsigned int u; float f; } t;
    t.u = u.x << 16;         d[0] = t.f;
    t.u = u.x & 0xffff0000u; d[1] = t.f;
    t.u = u.y << 16;         d[2] = t.f;
    t.u = u.y & 0xffff0000u; d[3] = t.f;
    t.u = u.z << 16;         d[4] = t.f;
    t.u = u.z & 0xffff0000u; d[5] = t.f;
    t.u = u.w << 16;         d[6] = t.f;
    t.u = u.w & 0xffff0000u; d[7] = t.f;
}
// acc[k] += w * bf16(u)[k], 8 elements
__device__ inline void fma8(float* acc, uint4 u, float w) {
    union { unsigned int u; float f; } t;
    t.u = u.x << 16;         acc[0] += w * t.f;
    t.u = u.x & 0xffff0000u; acc[1] += w * t.f;
    t.u = u.y << 16;         acc[2] += w * t.f;
    t.u = u.y & 0xffff0000u; acc[3] += w * t.f;
    t.u = u.z << 16;         acc[4] += w * t.f;
    t.u = u.z & 0xffff0000u; acc[5] += w * t.f;
    t.u = u.w << 16;         acc[6] += w * t.f;
    t.u = u.w & 0xffff0000u; acc[7] += w * t.f;
}
// direct global -> LDS DMA, 16 bytes per lane (gfx950 global_load_lds_dwordx4)
__device__ __forceinline__ void g2lds16(const unsigned short* g, unsigned short* l) {
    __builtin_amdgcn_global_load_lds(
        (const __attribute__((address_space(1))) unsigned int*)g,
        (__attribute__((address_space(3))) unsigned int*)l,
        16, 0, 0);
}

// bijective XCD swizzle (m204)
__device__ inline void xcd_tile(int* m0, int* n0, int tm, int tn) {
    int nwg  = gridDim.x * gridDim.y;
    int wgid = blockIdx.x + blockIdx.y * gridDim.x;
    int q = nwg >> 3, r = nwg & 7;
    int xcd = wgid & 7, pos = wgid >> 3;
    int nid = (xcd < r ? xcd * (q + 1) : r * (q + 1) + (xcd - r) * q) + pos;
    int gy = gridDim.y;
    int bx = nid / gy;
    int by = nid - bx * gy;
    *m0 = bx * tm;
    *n0 = by * tn;
}

// ---------------------------------------------------------------------------
// PREP mega-kernel: three independent preprocessing stages in one dispatch
// (they were serialized on the single stream as 3 launches):
//   blocks [0, LN_BLOCKS)                     : LayerNorm rows (4 rows/block)
//   blocks [LN_BLOCKS, LN_BLOCKS+TR_BLOCKS)   : 6-way weight transpose->bf16
//   blocks [.., +CNT_BLOCKS)                  : degree count (atomicAdd)
// ---------------------------------------------------------------------------
__global__ __launch_bounds__(256) void prep_kernel(
    const float* __restrict__ ent, const float* __restrict__ rel,
    const float* __restrict__ ge, const float* __restrict__ be,
    const float* __restrict__ gr, const float* __restrict__ br,
    unsigned short* __restrict__ xb, unsigned short* __restrict__ rlnb,
    const float* __restrict__ Wh, const float* __restrict__ Wt_,
    const float* __restrict__ We, const float* __restrict__ Wr,
    const float* __restrict__ W1, const float* __restrict__ W2,
    unsigned short* __restrict__ WtP, unsigned short* __restrict__ WtR,
    unsigned short* __restrict__ W1t, unsigned short* __restrict__ W2t,
    const int* __restrict__ dst, int* __restrict__ deg)
{
    int blk = blockIdx.x;
    if (blk < LN_BLOCKS) {
        int row = blk * 4 + (threadIdx.x >> 6);
        if (row >= N_NODES + N_REL) return;
        const float *in, *g, *b; unsigned short* out; int r;
        if (row < N_NODES) { in = ent; g = ge; b = be; out = xb;   r = row; }
        else               { in = rel; g = gr; b = br; out = rlnb; r = row - N_NODES; }
        int tid = threadIdx.x & 63;
        const float4 v = *(const float4*)(in + (size_t)r * FDIM + tid * 4);
        float s = v.x + v.y + v.z + v.w;
        float q = v.x * v.x + v.y * v.y + v.z * v.z + v.w * v.w;
        #pragma unroll
        for (int d = 1; d < 64; d <<= 1) { s += __shfl_xor(s, d); q += __shfl_xor(q, d); }
        float mean = s * (1.0f / FDIM);
        float var  = q * (1.0f / FDIM) - mean * mean;
        float inv  = rsqrtf(var + 1e-5f);
        float4 gg = *(const float4*)(g + tid * 4);
        float4 bb = *(const float4*)(b + tid * 4);
        ushort4 o;
        o.x = f2bf((v.x - mean) * inv * gg.x + bb.x);
        o.y = f2bf((v.y - mean) * inv * gg.y + bb.y);
        o.z = f2bf((v.z - mean) * inv * gg.z + bb.z);
        o.w = f2bf((v.w - mean) * inv * gg.w + bb.w);
        *(ushort4*)(out + (size_t)r * FDIM + tid * 4) = o;
    } else if (blk < LN_BLOCKS + TR_BLOCKS) {
        int idx = (blk - LN_BLOCKS) * 256 + threadIdx.x;
        if (idx < 196608) {
            int seg = idx >> 16, r = idx & 65535;
            const float* W = (seg == 0) ? Wh : (seg == 1) ? Wt_ : We;
            int n = r >> 8, k = r & 255;
            WtP[idx] = f2bf(W[k * 256 + n]);
        } else if (idx < 262144) {
            int r = idx - 196608;
            int n = r >> 8, k = r & 255;
            WtR[r] = f2bf(Wr[k * 256 + n]);
        } else if (idx < 524288) {
            int r = idx - 262144;                 // K=256, N=1024
            int n = r >> 8, k = r & 255;
            W1t[r] = f2bf(W1[k * 1024 + n]);
        } else {
            int r = idx - 524288;                 // K=1024, N=256
            int n = r >> 10, k = r & 1023;
            W2t[r] = f2bf(W2[k * 256 + n]);
        }
    } else {
        int i = (blk - LN_BLOCKS - TR_BLOCKS) * 256 + threadIdx.x;
        if (i < N_EDGES) atomicAdd(&deg[dst[i]], 1);
    }
}

// ---------------------------------------------------------------------------
// bf16 MFMA GEMM (B^T): C[M,N] = A[M,K] @ Bt[N,K]^T  (+bias)(relu)(+add)
// 128x128 tile, 4 waves, 4x4 16x16x32 frags/wave, BK=32.
// Double-buffered LDS + single barrier per K-step + XCD-aware swizzle.
// ---------------------------------------------------------------------------
__global__ __launch_bounds__(256) void mfma_gemm_bt(
    const unsigned short* __restrict__ A, const unsigned short* __restrict__ Bt,
    const float* __restrict__ bias, const float* __restrict__ add,
    float* __restrict__ Cf, unsigned short* __restrict__ Cb,
    int M, int K, int N, int relu)
{
    __shared__ unsigned short As[2][128 * 32];
    __shared__ unsigned short Bs[2][128 * 32];
    int tid  = threadIdx.x;
    int wave = tid >> 6, lane = tid & 63;
    int quad = lane >> 4, l16 = lane & 15;
    int m0, n0;
    xcd_tile(&m0, &n0, 128, 128);
    int wr = (wave >> 1) * 64, wc = (wave & 1) * 64;

    f32x4 acc[4][4] = {};

    int cA = tid, cB = tid + 256;
    int rA0 = cA >> 2, kA0 = (cA & 3) * 8;
    int rB0 = cB >> 2, kB0 = (cB & 3) * 8;
    int rA = m0 + rA0; if (rA >= M) rA = M - 1;
    int rB = m0 + rB0; if (rB >= M) rB = M - 1;
    const unsigned short* gA0 = A + (size_t)rA * K + kA0;
    const unsigned short* gA1 = A + (size_t)rB * K + kB0;
    const unsigned short* gB0 = Bt + (size_t)(n0 + rA0) * K + kA0;
    const unsigned short* gB1 = Bt + (size_t)(n0 + rB0) * K + kB0;

    g2lds16(gA0, As[0] + cA * 8);
    g2lds16(gA1, As[0] + cB * 8);
    g2lds16(gB0, Bs[0] + cA * 8);
    g2lds16(gB1, Bs[0] + cB * 8);
    __syncthreads();

    int cur = 0;
    for (int k0 = 0; k0 < K; k0 += 32) {
        int k1 = k0 + 32;
        if (k1 < K) {
            int nb = cur ^ 1;
            g2lds16(gA0 + k1, As[nb] + cA * 8);
            g2lds16(gA1 + k1, As[nb] + cB * 8);
            g2lds16(gB0 + k1, Bs[nb] + cA * 8);
            g2lds16(gB1 + k1, Bs[nb] + cB * 8);
        }
        short8 af[4], bfr[4];
        #pragma unroll
        for (int i = 0; i < 4; ++i)
            af[i] = *(const short8*)(As[cur] + (wr + i * 16 + l16) * 32 + quad * 8);
        #pragma unroll
        for (int j = 0; j < 4; ++j)
            bfr[j] = *(const short8*)(Bs[cur] + (wc + j * 16 + l16) * 32 + quad * 8);
        #pragma unroll
        for (int i = 0; i < 4; ++i)
            #pragma unroll
            for (int j = 0; j < 4; ++j)
                acc[i][j] = __builtin_amdgcn_mfma_f32_16x16x32_bf16(
                    af[i], bfr[j], acc[i][j], 0, 0, 0);
        __syncthreads();
        cur ^= 1;
    }

    #pragma unroll
    for (int i = 0; i < 4; ++i) {
        #pragma unroll
        for (int j = 0; j < 4; ++j) {
            int col = n0 + wc + j * 16 + l16;
            float bsv = bias ? bias[col] : 0.0f;
            #pragma unroll
            for (int r = 0; r < 4; ++r) {
                int row = m0 + wr + i * 16 + quad * 4 + r;
                if (row < M) {
                    float v = acc[i][j][r] + bsv;
                    if (relu) v = fmaxf(v, 0.0f);
                    if (add)  v += add[(size_t)row * N + col];
                    if (Cf) Cf[(size_t)row * N + col] = v;
                    else    Cb[(size_t)row * N + col] = f2bf(v);
                }
            }
        }
    }
}

// ---------------------------------------------------------------------------
// 64x128-tile variant (small grids / long K, e.g. FFN2): 4 waves, 4x2 frags.
// ---------------------------------------------------------------------------
__global__ __launch_bounds__(256) void mfma_gemm64_bt(
    const unsigned short* __restrict__ A, const unsigned short* __restrict__ Bt,
    const float* __restrict__ bias, const float* __restrict__ add,
    float* __restrict__ Cf, int M, int K, int N)
{
    __shared__ unsigned short As[2][64 * 32];
    __shared__ unsigned short Bs[2][128 * 32];
    int tid  = threadIdx.x;
    int wave = tid >> 6, lane = tid & 63;
    int quad = lane >> 4, l16 = lane & 15;
    int m0, n0;
    xcd_tile(&m0, &n0, 64, 128);
    int wc = wave * 32;

    f32x4 acc[4][2] = {};

    int rA0 = tid >> 2, kA0 = (tid & 3) * 8;
    int cB0 = tid, cB1 = tid + 256;
    int rB0 = cB0 >> 2, kB0 = (cB0 & 3) * 8;
    int rB1 = cB1 >> 2, kB1 = (cB1 & 3) * 8;
    int rA = m0 + rA0; if (rA >= M) rA = M - 1;
    const unsigned short* gA  = A + (size_t)rA * K + kA0;
    const unsigned short* gB0 = Bt + (size_t)(n0 + rB0) * K + kB0;
    const unsigned short* gB1 = Bt + (size_t)(n0 + rB1) * K + kB1;

    g2lds16(gA,  As[0] + tid * 8);
    g2lds16(gB0, Bs[0] + cB0 * 8);
    g2lds16(gB1, Bs[0] + cB1 * 8);
    __syncthreads();

    int cur = 0;
    for (int k0 = 0; k0 < K; k0 += 32) {
        short8 af[4], bfr[2];
        #pragma unroll
        for (int i = 0; i < 4; ++i)
            af[i] = *(const short8*)(As[cur] + (i * 16 + l16) * 32 + quad * 8);
        #pragma unroll
        for (int j = 0; j < 2; ++j)
            bfr[j] = *(const short8*)(Bs[cur] + (wc + j * 16 + l16) * 32 + quad * 8);
        int k1 = k0 + 32;
        if (k1 < K) {
            int nb = cur ^ 1;
            g2lds16(gA + k1,  As[nb] + tid * 8);
            g2lds16(gB0 + k1, Bs[nb] + cB0 * 8);
            g2lds16(gB1 + k1, Bs[nb] + cB1 * 8);
        }
        #pragma unroll
        for (int i = 0; i < 4; ++i)
            #pragma unroll
            for (int j = 0; j < 2; ++j)
                acc[i][j] = __builtin_amdgcn_mfma_f32_16x16x32_bf16(
                    af[i], bfr[j], acc[i][j], 0, 0, 0);
        __syncthreads();
        cur ^= 1;
    }

    #pragma unroll
    for (int i = 0; i < 4; ++i) {
        #pragma unroll
        for (int j = 0; j < 2; ++j) {
            int col = n0 + wc + j * 16 + l16;
            float bsv = bias ? bias[col] : 0.0f;
            #pragma unroll
            for (int r = 0; r < 4; ++r) {
                int row = m0 + i * 16 + quad * 4 + r;
                if (row < M) {
                    float v = acc[i][j][r] + bsv;
                    if (add) v += add[(size_t)row * N + col];
                    Cf[(size_t)row * N + col] = v;
                }
            }
        }
    }
}

// ---------------------------------------------------------------------------
// Graph plumbing: 3-phase parallel scan -> scatter (count lives in prep)
// ---------------------------------------------------------------------------
__global__ __launch_bounds__(256) void scan1_kernel(
    const int* __restrict__ deg, int* __restrict__ offsets, int* __restrict__ bsum, int n)
{
    __shared__ int tmp[256];
    int tid = threadIdx.x;
    int i = blockIdx.x * 256 + tid;
    int v = (i < n) ? deg[i] : 0;
    tmp[tid] = v;
    __syncthreads();
    for (int d = 1; d < 256; d <<= 1) {
        int u = (tid >= d) ? tmp[tid - d] : 0;
        __syncthreads();
        tmp[tid] += u;
        __syncthreads();
    }
    if (i < n) offsets[i] = tmp[tid] - v;
    if (tid == 255) bsum[blockIdx.x] = tmp[255];
}

__global__ __launch_bounds__(128) void scan2_kernel(int* __restrict__ bsum, int nb)
{
    __shared__ int tmp[128];
    int tid = threadIdx.x;
    int v = (tid < nb) ? bsum[tid] : 0;
    tmp[tid] = v;
    __syncthreads();
    for (int d = 1; d < 128; d <<= 1) {
        int u = (tid >= d) ? tmp[tid - d] : 0;
        __syncthreads();
        tmp[tid] += u;
        __syncthreads();
    }
    if (tid < nb) bsum[tid] = tmp[tid] - v;
}

__global__ __launch_bounds__(256) void scan3_kernel(
    const int* __restrict__ deg, int* __restrict__ offsets,
    const int* __restrict__ bsum, int* __restrict__ cursor,
    float* __restrict__ logdeg, int n, int E)
{
    int i = blockIdx.x * 256 + threadIdx.x;
    if (i < n) {
        int o = offsets[i] + bsum[blockIdx.x];
        offsets[i] = o;
        cursor[i]  = o;
        logdeg[i]  = logf((float)deg[i]);
    }
    if (i == 0) offsets[n] = E;
}

__global__ void scatter_kernel(const int* __restrict__ dst, const int* __restrict__ src,
                               const int* __restrict__ rid, int* __restrict__ cursor,
                               int* __restrict__ csr_src, int* __restrict__ csr_rid, int E)
{
    int i = blockIdx.x * blockDim.x + threadIdx.x;
    if (i < E) {
        int p = atomicAdd(&cursor[dst[i]], 1);
        csr_src[p] = src[i];
        csr_rid[p] = rid[i];
    }
}

// ---------------------------------------------------------------------------
// FUSED edge attention + PPR hop 1 (r9-proven). One wave per dst node.
// ---------------------------------------------------------------------------
__global__ __launch_bounds__(256) void score_hop1_kernel(
    const unsigned short* __restrict__ proj,   // [N,768]: fh | ftl | fen
    const unsigned short* __restrict__ frel,   // [R,256] bf16
    const float* __restrict__ attn,
    const int* __restrict__ csr_src, const int* __restrict__ csr_rid,
    const int* __restrict__ offsets, const float* __restrict__ logdeg,
    float* __restrict__ csr_a, float* __restrict__ invd,
    unsigned short* __restrict__ fout, int n)
{
    int node = blockIdx.x * 4 + (threadIdx.x >> 6);
    if (node >= n) return;
    int tid = threadIdx.x & 63;
    int g = tid >> 4, li = tid & 15;
    int start = offsets[node], end = offsets[node + 1];
    float scale = logdeg[node] * (1.0f / 32.0f);

    float tv[16], at[16];
    {
        const unsigned short* tp = proj + (size_t)node * 768 + 256 + li * 16;
        uint4 a0 = *(const uint4*)tp, a1 = *(const uint4*)(tp + 8);
        unpack8(tv, a0); unpack8(tv + 8, a1);
        const float4* ap = (const float4*)(attn + li * 16);
        float4 f;
        f = ap[0]; at[0] = f.x; at[1] = f.y; at[2]  = f.z; at[3]  = f.w;
        f = ap[1]; at[4] = f.x; at[5] = f.y; at[6]  = f.z; at[7]  = f.w;
        f = ap[2]; at[8] = f.x; at[9] = f.y; at[10] = f.z; at[11] = f.w;
        f = ap[3]; at[12] = f.x; at[13] = f.y; at[14] = f.z; at[15] = f.w;
    }

    float acc[16] = {};
    float denom = 0.f;
    for (int p = start; p < end; p += 4) {
        int e = p + g;
        bool va = e < end;
        int q = va ? e : end - 1;
        int s = csr_src[q], r = csr_rid[q];
        const unsigned short* hp = proj + (size_t)s * 768 + li * 16;
        const unsigned short* rp = frel + (size_t)r * FDIM + li * 16;
        uint4 h0 = *(const uint4*)hp,        h1 = *(const uint4*)(hp + 8);
        uint4 r0 = *(const uint4*)rp,        r1 = *(const uint4*)(rp + 8);
        uint4 e0 = *(const uint4*)(hp + 512), e1 = *(const uint4*)(hp + 520);
        float hv[16], rv[16];
        unpack8(hv, h0); unpack8(hv + 8, h1);
        unpack8(rv, r0); unpack8(rv + 8, r1);
        float sum = 0.f;
        #pragma unroll
        for (int k = 0; k < 16; ++k) {
            float m = hv[k] * tv[k] * rv[k];
            m = (m > 0.f) ? m : 0.2f * m;
            sum += m * at[k];
        }
        sum += __shfl_xor(sum, 1);               // both lanes of pair: head sum
        float ex = va ? __expf(sum * scale) : 0.f;
        if (va && ((li & 1) == 0))
            csr_a[(size_t)e * NHEAD + (li >> 1)] = ex;
        denom += ex;                             // per-lane: its head's partial
        fma8(acc + 0, e0, ex);                   // unnormalized weighted fen
        fma8(acc + 8, e1, ex);
    }
    denom += __shfl_xor(denom, 16);
    denom += __shfl_xor(denom, 32);
    #pragma unroll
    for (int k = 0; k < 16; ++k) {
        acc[k] += __shfl_xor(acc[k], 16);
        acc[k] += __shfl_xor(acc[k], 32);
    }
    float wn = 1.0f / denom;                     // this lane's head denom
    if (g == 0 && (li & 1) == 0)
        invd[node * NHEAD + (li >> 1)] = wn;
    if (g == 0) {
        const unsigned short* f0p = proj + (size_t)node * 768 + 512 + li * 16;
        uint4 f0a = *(const uint4*)(f0p);
        uint4 f0b = *(const uint4*)(f0p + 8);
        float f0[16];
        unpack8(f0, f0a); unpack8(f0 + 8, f0b);
        unsigned short o[16];
        #pragma unroll
        for (int k = 0; k < 16; ++k)
            o[k] = f2bf(0.9f * acc[k] * wn + 0.1f * f0[k]);
        uint4* dst4 = (uint4*)(fout + (size_t)node * FDIM + li * 16);
        dst4[0] = *(uint4*)(o);
        dst4[1] = *(uint4*)(o + 8);
    }
}

// ---------------------------------------------------------------------------
// One PPR hop (bf16) — r1-proven structure. One wave per dst node (4/block);
// 16 lanes per edge, 16 edges in flight; cross-group reduce once/node.
// ---------------------------------------------------------------------------
__global__ __launch_bounds__(256) void diffuse_kernel(
    const unsigned short* __restrict__ fin, int fin_stride,
    const unsigned short* __restrict__ feat0,   // stride 768 (fen in proj)
    const float* __restrict__ a, const float* __restrict__ invd,
    const int* __restrict__ csr_src,
    const int* __restrict__ offsets, unsigned short* __restrict__ fout, int n)
{
    int node = blockIdx.x * 4 + (threadIdx.x >> 6);
    if (node >= n) return;
    int tid = threadIdx.x & 63;
    int g = tid >> 4, li = tid & 15;
    int hh = li >> 1;
    int start = offsets[node], end = offsets[node + 1];
    float wnorm = invd[node * NHEAD + hh];
    float acc[16] = {};

    for (int p = start; p < end; p += 16) {
        uint4 u0[4], u1[4]; float w[4];
        #pragma unroll
        for (int t = 0; t < 4; ++t) {
            int pe = p + t * 4 + g;
            int q = (pe < end) ? pe : end - 1;
            int s = csr_src[q];
            w[t] = (pe < end) ? a[(size_t)q * NHEAD + hh] : 0.0f;
            const unsigned short* rp = fin + (size_t)s * fin_stride + li * 16;
            u0[t] = *(const uint4*)(rp);
            u1[t] = *(const uint4*)(rp + 8);
        }
        #pragma unroll
        for (int t = 0; t < 4; ++t) {
            fma8(acc + 0, u0[t], w[t]);
            fma8(acc + 8, u1[t], w[t]);
        }
    }
    #pragma unroll
    for (int k = 0; k < 16; ++k) {
        acc[k] += __shfl_xor(acc[k], 16);
        acc[k] += __shfl_xor(acc[k], 32);
    }
    if (g == 0) {
        const unsigned short* f0p = feat0 + (size_t)node * 768 + li * 16;
        uint4 f0a = *(const uint4*)(f0p);
        uint4 f0b = *(const uint4*)(f0p + 8);
        float f0[16];
        unpack8(f0, f0a); unpack8(f0 + 8, f0b);
        unsigned short o[16];
        #pragma unroll
        for (int k = 0; k < 16; ++k)
            o[k] = f2bf(0.9f * acc[k] * wnorm + 0.1f * f0[k]);
        uint4* dst4 = (uint4*)(fout + (size_t)node * FDIM + li * 16);
        dst4[0] = *(uint4*)(o);
        dst4[1] = *(uint4*)(o + 8);
    }
}

// ---------------------------------------------------------------------------
// FINAL PPR hop fused with residual + pre-LN. Same gather loop as
// diffuse_kernel, but instead of materializing the bf16 hop-5 buffer:
//   r[k] = 0.9*acc[k]*wn + 0.1*fen[k] + ent[k]     (fp32, one less rounding)
//   rst  = r (fp32 out), y = LN(r) (bf16 out)
// After the cross-group xor-reduce every group's 16 lanes hold the FULL
// 256-feature row (lane li owns features [li*16, li*16+16)), so the LN row
// reduction is a 4-step shfl_xor within the 16-lane group. Saves the hb0
// round-trip (~20 MB) + one launch vs diffuse + rst_ln.
// ---------------------------------------------------------------------------
__global__ __launch_bounds__(256) void diffuse_rstln_kernel(
    const unsigned short* __restrict__ fin, int fin_stride,
    const unsigned short* __restrict__ feat0,   // stride 768 (fen in proj)
    const float* __restrict__ a, const float* __restrict__ invd,
    const int* __restrict__ csr_src, const int* __restrict__ offsets,
    const float* __restrict__ ent,
    const float* __restrict__ lng, const float* __restrict__ lnb,
    float* __restrict__ rst, unsigned short* __restrict__ y, int n)
{
    int node = blockIdx.x * 4 + (threadIdx.x >> 6);
    if (node >= n) return;
    int tid = threadIdx.x & 63;
    int g = tid >> 4, li = tid & 15;
    int hh = li >> 1;
    int start = offsets[node], end = offsets[node + 1];
    float wnorm = invd[node * NHEAD + hh];
    float acc[16] = {};

    for (int p = start; p < end; p += 16) {
        uint4 u0[4], u1[4]; float w[4];
        #pragma unroll
        for (int t = 0; t < 4; ++t) {
            int pe = p + t * 4 + g;
            int q = (pe < end) ? pe : end - 1;
            int s = csr_src[q];
            w[t] = (pe < end) ? a[(size_t)q * NHEAD + hh] : 0.0f;
            const unsigned short* rp = fin + (size_t)s * fin_stride + li * 16;
            u0[t] = *(const uint4*)(rp);
            u1[t] = *(const uint4*)(rp + 8);
        }
        #pragma unroll
        for (int t = 0; t < 4; ++t) {
            fma8(acc + 0, u0[t], w[t]);
            fma8(acc + 8, u1[t], w[t]);
        }
    }
    #pragma unroll
    for (int k = 0; k < 16; ++k) {
        acc[k] += __shfl_xor(acc[k], 16);
        acc[k] += __shfl_xor(acc[k], 32);   // all 64 lanes: full sums
    }

    // residual in fp32 (duplicated across groups; identical values per li)
    const unsigned short* f0p = feat0 + (size_t)node * 768 + li * 16;
    uint4 f0a = *(const uint4*)(f0p);
    uint4 f0b = *(const uint4*)(f0p + 8);
    float f0[16];
    unpack8(f0, f0a); unpack8(f0 + 8, f0b);
    const float* ep = ent + (size_t)node * FDIM + li * 16;
    float4 e0 = *(const float4*)(ep),     e1 = *(const float4*)(ep + 4);
    float4 e2 = *(const float4*)(ep + 8), e3 = *(const float4*)(ep + 12);
    float ev[16] = { e0.x, e0.y, e0.z, e0.w, e1.x, e1.y, e1.z, e1.w,
                     e2.x, e2.y, e2.z, e2.w, e3.x, e3.y, e3.z, e3.w };
    float r[16];
    #pragma unroll
    for (int k = 0; k < 16; ++k)
        r[k] = 0.9f * acc[k] * wnorm + 0.1f * f0[k] + ev[k];

    // LN reduction: lanes li=0..15 of each group hold the whole row
    float s = 0.f, q = 0.f;
    #pragma unroll
    for (int k = 0; k < 16; ++k) { s += r[k]; q += r[k] * r[k]; }
    #pragma unroll
    for (int d = 1; d < 16; d <<= 1) { s += __shfl_xor(s, d); q += __shfl_xor(q, d); }
    float mean = s * (1.0f / FDIM);
    float var  = q * (1.0f / FDIM) - mean * mean;
    float inv  = rsqrtf(var + 1e-5f);

    if (g == 0) {
        float* rp4 = rst + (size_t)node * FDIM + li * 16;
        *(float4*)(rp4 + 0)  = make_float4(r[0],  r[1],  r[2],  r[3]);
        *(float4*)(rp4 + 4)  = make_float4(r[4],  r[5],  r[6],  r[7]);
        *(float4*)(rp4 + 8)  = make_float4(r[8],  r[9],  r[10], r[11]);
        *(float4*)(rp4 + 12) = make_float4(r[12], r[13], r[14], r[15]);
        const float* gp = lng + li * 16;
        const float* bp = lnb + li * 16;
        unsigned short o[16];
        #pragma unroll
        for (int k = 0; k < 16; ++k)
            o[k] = f2bf((r[k] - mean) * inv * gp[k] + bp[k]);
        uint4* dst4 = (uint4*)(y + (size_t)node * FDIM + li * 16);
        dst4[0] = *(uint4*)(o);
        dst4[1] = *(uint4*)(o + 8);
    }
}

// ---------------------------------------------------------------------------
extern "C" void kernel_launch(void* const* d_in, const int* in_sizes, int n_in,
                              void* d_out, int out_size, void* d_ws, size_t ws_size,
                              hipStream_t stream)
{
    const float* ent_feat = (const float*)d_in[0];
    const float* rel_feat = (const float*)d_in[1];
    const float* W_head   = (const float*)d_in[2];
    const float* W_tail   = (const float*)d_in[3];
    const float* W_ent    = (const float*)d_in[4];
    const float* W_rel    = (const float*)d_in[5];
    const float* attn     = (const float*)d_in[6];
    const float* ln_ent_g = (const float*)d_in[7];
    const float* ln_ent_b = (const float*)d_in[8];
    const float* ln_rel_g = (const float*)d_in[9];
    const float* ln_rel_b = (const float*)d_in[10];
    const float* ln_ff_g  = (const float*)d_in[11];
    const float* ln_ff_b  = (const float*)d_in[12];
    const float* W1       = (const float*)d_in[13];
    const float* b1       = (const float*)d_in[14];
    const float* W2       = (const float*)d_in[15];
    const float* b2       = (const float*)d_in[16];
    const int*   src      = (const int*)d_in[17];
    const int*   dst      = (const int*)d_in[18];
    const int*   rid      = (const int*)d_in[19];
    float* out = (float*)d_out;

    // ---- workspace carve (bytes, 256-aligned) ----
    char* base = (char*)d_ws;
    auto carve = [&](size_t bytes) { char* p = base; base += (bytes + 255) & ~(size_t)255; return p; };
    unsigned short* xb    = (unsigned short*)carve((size_t)N_NODES * FDIM * 2);
    unsigned short* projb = (unsigned short*)carve((size_t)N_NODES * 768 * 2);
    unsigned short* rlnb  = (unsigned short*)carve((size_t)N_REL * FDIM * 2);
    unsigned short* frelb = (unsigned short*)carve((size_t)N_REL * FDIM * 2);
    unsigned short* WtP   = (unsigned short*)carve((size_t)768 * FDIM * 2);
    unsigned short* WtR   = (unsigned short*)carve((size_t)FDIM * FDIM * 2);
    unsigned short* W1t   = (unsigned short*)carve((size_t)1024 * FDIM * 2);
    unsigned short* W2t   = (unsigned short*)carve((size_t)FDIM * 1024 * 2);
    unsigned short* hb0   = (unsigned short*)carve((size_t)N_NODES * FDIM * 2);
    unsigned short* hb1   = (unsigned short*)carve((size_t)N_NODES * FDIM * 2);
    unsigned short* yb    = (unsigned short*)carve((size_t)N_NODES * FDIM * 2);
    unsigned short* t1b   = (unsigned short*)carve((size_t)N_NODES * 1024 * 2);
    float* rst     = (float*)carve((size_t)N_NODES * FDIM * 4);
    float* csr_a   = (float*)carve(((size_t)N_EDGES * NHEAD + 256) * 4);
    float* invd    = (float*)carve((size_t)N_NODES * NHEAD * 4);
    int*   csr_src = (int*)carve((size_t)(N_EDGES + 64) * 4);
    int*   csr_rid = (int*)carve((size_t)(N_EDGES + 64) * 4);
    int*   deg     = (int*)carve((size_t)N_NODES * 4);
    float* logdeg  = (float*)carve((size_t)N_NODES * 4);
    int*   offsets = (int*)carve((size_t)(N_NODES + 1) * 4);
    int*   cursor  = (int*)carve((size_t)N_NODES * 4);
    int*   bsum    = (int*)carve((size_t)SCAN_BLOCKS * 4);

    hipMemsetAsync(deg, 0, (size_t)N_NODES * 4, stream);

    // fused preprocessing: LN rows + 6 weight transposes + degree count
    prep_kernel<<<LN_BLOCKS + TR_BLOCKS + CNT_BLOCKS, 256, 0, stream>>>(
        ent_feat, rel_feat, ln_ent_g, ln_ent_b, ln_rel_g, ln_rel_b, xb, rlnb,
        W_head, W_tail, W_ent, W_rel, W1, W2, WtP, WtR, W1t, W2t,
        dst, deg);

    // fused projection GEMM: proj[N,768] = xb @ [Wh|Wt|We]  (bf16 out)
    dim3 gproj((N_NODES + 127) / 128, 768 / 128);
    mfma_gemm_bt<<<gproj, 256, 0, stream>>>(xb, WtP, nullptr, nullptr, nullptr, projb,
                                            N_NODES, FDIM, 768, 0);
    dim3 grel(1, FDIM / 128);
    mfma_gemm_bt<<<grel, 256, 0, stream>>>(rlnb, WtR, nullptr, nullptr, nullptr, frelb,
                                           N_REL, FDIM, FDIM, 0);

    // CSR build (scan -> scatter; count already done in prep)
    scan1_kernel<<<SCAN_BLOCKS, 256, 0, stream>>>(deg, offsets, bsum, N_NODES);
    scan2_kernel<<<1, 128, 0, stream>>>(bsum, SCAN_BLOCKS);
    scan3_kernel<<<SCAN_BLOCKS, 256, 0, stream>>>(deg, offsets, bsum, cursor, logdeg,
                                                  N_NODES, N_EDGES);
    scatter_kernel<<<(N_EDGES + 255) / 256, 256, 0, stream>>>(dst, src, rid, cursor,
                                                              csr_src, csr_rid, N_EDGES);

    // FUSED attention scores + hop 1 (writes csr_a, invd, hb0)
    score_hop1_kernel<<<(N_NODES + 3) / 4, 256, 0, stream>>>(
        projb, frelb, attn, csr_src, csr_rid, offsets, logdeg,
        csr_a, invd, hb0, N_NODES);

    // hops 2-4: hb0 -> hb1 -> hb0 -> hb1
    const unsigned short* fen = projb + 512;
    int gdif = (N_NODES + 3) / 4;
    diffuse_kernel<<<gdif, 256, 0, stream>>>(hb0, FDIM, fen, csr_a, invd, csr_src, offsets, hb1, N_NODES);
    diffuse_kernel<<<gdif, 256, 0, stream>>>(hb1, FDIM, fen, csr_a, invd, csr_src, offsets, hb0, N_NODES);
    diffuse_kernel<<<gdif, 256, 0, stream>>>(hb0, FDIM, fen, csr_a, invd, csr_src, offsets, hb1, N_NODES);
    // hop 5 fused with residual + pre-LN (writes rst fp32 + yb bf16)
    diffuse_rstln_kernel<<<gdif, 256, 0, stream>>>(
        hb1, FDIM, fen, csr_a, invd, csr_src, offsets,
        ent_feat, ln_ff_g, ln_ff_b, rst, yb, N_NODES);

    // FFN1: t1 = relu(y@W1 + b1) [bf16], 128x128 tiles
    dim3 gff1((N_NODES + 127) / 128, 1024 / 128);
    mfma_gemm_bt<<<gff1, 256, 0, stream>>>(yb, W1t, b1, nullptr, nullptr, t1b,
                                           N_NODES, FDIM, 1024, 1);
    // FFN2: out = t1@W2 + b2 + rst, 64x128 tiles
    dim3 gff2((N_NODES + 63) / 64, FDIM / 128);
    mfma_gemm64_bt<<<gff2, 256, 0, stream>>>(t1b, W2t, b2, rst, out,
                                             N_NODES, 1024, FDIM);
}